// Round 11
// baseline (19807.274 us; speedup 1.0000x reference)
//
#include <hip/hip_runtime.h>
#include <cstdint>
#include <cstddef>

#ifndef PARTITIONABLE
#define PARTITIONABLE 1
#endif

namespace {
constexpr int kBatch  = 4096;
constexpr int kEmb    = 128;
constexpr int kHid    = 512;
constexpr int kVoc    = 2048;
constexpr int kMaxLen = 64;
constexpr int kTopK   = 40;
constexpr int kBos = 1, kEos = 2, kPad = 0;
constexpr int kEffMin = 20;
constexpr float kNeg  = -1.0e9f;
constexpr float kTiny = 1.17549435082228751e-38f;
}

typedef __bf16 bf16x8 __attribute__((ext_vector_type(8)));
typedef float  f32x4  __attribute__((ext_vector_type(4)));

__host__ __device__ inline void tf2x32(uint32_t k0, uint32_t k1,
                                       uint32_t x0, uint32_t x1,
                                       uint32_t& o0, uint32_t& o1) {
  uint32_t ks0 = k0, ks1 = k1, ks2 = k0 ^ k1 ^ 0x1BD11BDAu;
  x0 += ks0; x1 += ks1;
#define TFR(r) { x0 += x1; x1 = (x1 << (r)) | (x1 >> (32 - (r))); x1 ^= x0; }
  TFR(13) TFR(15) TFR(26) TFR(6)   x0 += ks1; x1 += ks2 + 1u;
  TFR(17) TFR(29) TFR(16) TFR(24)  x0 += ks2; x1 += ks0 + 2u;
  TFR(13) TFR(15) TFR(26) TFR(6)   x0 += ks0; x1 += ks1 + 3u;
  TFR(17) TFR(29) TFR(16) TFR(24)  x0 += ks1; x1 += ks2 + 4u;
  TFR(13) TFR(15) TFR(26) TFR(6)   x0 += ks2; x1 += ks0 + 5u;
#undef TFR
  o0 = x0; o1 = x1;
}

__device__ __forceinline__ float xla_tanh(float x) {
  float ax = fabsf(x);
  float xc = fminf(fmaxf(x, -9.0f), 9.0f);
  float x2 = __fmul_rn(xc, xc);
  float num = -2.76076847742355e-16f;
  num = __fadd_rn(__fmul_rn(x2, num), 2.00018790482477e-13f);
  num = __fadd_rn(__fmul_rn(x2, num), -8.60467152213735e-11f);
  num = __fadd_rn(__fmul_rn(x2, num), 5.12229709037114e-08f);
  num = __fadd_rn(__fmul_rn(x2, num), 1.48572235717979e-05f);
  num = __fadd_rn(__fmul_rn(x2, num), 6.37261928875436e-04f);
  num = __fadd_rn(__fmul_rn(x2, num), 4.89352455891786e-03f);
  num = __fmul_rn(xc, num);
  float den = 1.19825839466702e-06f;
  den = __fadd_rn(__fmul_rn(x2, den), 1.18534705686654e-04f);
  den = __fadd_rn(__fmul_rn(x2, den), 2.26843463243900e-03f);
  den = __fadd_rn(__fmul_rn(x2, den), 4.89352518554385e-03f);
  return (ax < 4.0e-04f) ? x : __fdiv_rn(num, den);
}

__device__ __forceinline__ float xla_sigmoid(float x) {
  return __fdiv_rn(1.0f, __fadd_rn(1.0f, expf(-x)));
}

__device__ __forceinline__ void gl_lds16(const void* g, void* l) {
  __builtin_amdgcn_global_load_lds(
      (const __attribute__((address_space(1))) void*)g,
      (__attribute__((address_space(3))) void*)l, 16, 0, 0);
}

__device__ __forceinline__ void split3(float a, __bf16& a0, __bf16& a1, __bf16& a2) {
  a0 = (__bf16)a;
  float r1 = __fsub_rn(a, (float)a0);
  a1 = (__bf16)r1;
  float r2 = __fsub_rn(r1, (float)a1);
  a2 = (__bf16)r2;   // exact: 3x8 mantissa bits cover f32's 24
}

__device__ __forceinline__ float gru_h(float gir, float giz, float gin,
                                       float ghr, float ghz, float ghn,
                                       float hold) {
  float r = xla_sigmoid(__fadd_rn(gir, ghr));
  float u = xla_sigmoid(__fadd_rn(giz, ghz));
  float n = xla_tanh(__fadd_rn(gin, __fmul_rn(r, ghn)));
  float t1 = __fmul_rn(__fsub_rn(1.0f, u), n);
  float t2 = __fmul_rn(u, hold);
  return __fadd_rn(t1, t2);
}

#define MFMA9(c, A0_, A1_, A2_, B0_, B1_, B2_) do {                          \
    c = __builtin_amdgcn_mfma_f32_16x16x32_bf16(A2_, B2_, c, 0, 0, 0);       \
    c = __builtin_amdgcn_mfma_f32_16x16x32_bf16(A2_, B1_, c, 0, 0, 0);       \
    c = __builtin_amdgcn_mfma_f32_16x16x32_bf16(A1_, B2_, c, 0, 0, 0);       \
    c = __builtin_amdgcn_mfma_f32_16x16x32_bf16(A2_, B0_, c, 0, 0, 0);       \
    c = __builtin_amdgcn_mfma_f32_16x16x32_bf16(A1_, B1_, c, 0, 0, 0);       \
    c = __builtin_amdgcn_mfma_f32_16x16x32_bf16(A0_, B2_, c, 0, 0, 0);       \
    c = __builtin_amdgcn_mfma_f32_16x16x32_bf16(A1_, B0_, c, 0, 0, 0);       \
    c = __builtin_amdgcn_mfma_f32_16x16x32_bf16(A0_, B1_, c, 0, 0, 0);       \
    c = __builtin_amdgcn_mfma_f32_16x16x32_bf16(A0_, B0_, c, 0, 0, 0);       \
  } while (0)

// ---------------- f32 vector GEMM (init only; proven rounds 1-2) ------------
template <int ACT>
__global__ __launch_bounds__(256) void gemm2(
    const float* __restrict__ A0, const float* __restrict__ B0,
    const float* __restrict__ bias0, float* __restrict__ C0,
    const float* __restrict__ A1, const float* __restrict__ B1,
    const float* __restrict__ bias1, float* __restrict__ C1,
    int lda, int ldb, int ldc, int K) {
  __shared__ __attribute__((aligned(16))) float As[2][128 * 16];
  __shared__ __attribute__((aligned(16))) float Bs[2][16 * 128];

  const float* A    = blockIdx.z ? A1 : A0;
  const float* Bt   = blockIdx.z ? B1 : B0;
  const float* bias = blockIdx.z ? bias1 : bias0;
  float*       C    = blockIdx.z ? C1 : C0;

  const int tid = threadIdx.x;
  const int w = tid >> 6, l = tid & 63;
  const int bm = blockIdx.y * 128;
  const int bn = blockIdx.x * 128;
  const int tx = tid & 15, ty = tid >> 4;
  const int t3 = ty & 3;

  const int arow  = w * 16 + (l >> 2);
  const int agran = (l & 3) ^ ((l >> 2) & 3);
  const float* pA = A + (size_t)(bm + arow) * lda + agran * 4;
  const int bk = w * 2 + (l >> 5);
  const int bnc = (l & 31) * 4;
  const float* pB = Bt + (size_t)bk * ldb + bn + bnc;

  float acc[8][8];
#pragma unroll
  for (int i = 0; i < 8; ++i)
#pragma unroll
    for (int j = 0; j < 8; ++j) acc[i][j] = 0.0f;

  const int nt = K >> 4;
  gl_lds16(pA,            &As[0][w * 256]);
  gl_lds16(pA + 64 * lda, &As[0][(4 + w) * 256]);
  gl_lds16(pB,            &Bs[0][w * 256]);
  gl_lds16(pB + (size_t)8 * ldb, &Bs[0][(4 + w) * 256]);
  __syncthreads();

  for (int t = 0; t < nt; ++t) {
    const int cur = t & 1;
    if (t + 1 < nt) {
      const float* qA = pA + (t + 1) * 16;
      const float* qB = pB + (size_t)(t + 1) * 16 * ldb;
      gl_lds16(qA,            &As[cur ^ 1][w * 256]);
      gl_lds16(qA + 64 * lda, &As[cur ^ 1][(4 + w) * 256]);
      gl_lds16(qB,            &Bs[cur ^ 1][w * 256]);
      gl_lds16(qB + (size_t)8 * ldb, &Bs[cur ^ 1][(4 + w) * 256]);
    }
    const float* as = As[cur];
    const float* bs = Bs[cur];
#pragma unroll
    for (int g = 0; g < 4; ++g) {
      float4 bv0[4], bv1[4];
#pragma unroll
      for (int q = 0; q < 4; ++q) {
        bv0[q] = *(const float4*)&bs[(g * 4 + q) * 128 + tx * 4];
        bv1[q] = *(const float4*)&bs[(g * 4 + q) * 128 + 64 + tx * 4];
      }
#pragma unroll
      for (int ii = 0; ii < 8; ++ii) {
        float4 a = *(const float4*)&as[(ty + 16 * ii) * 16 + ((g ^ t3) * 4)];
        float ak[4] = {a.x, a.y, a.z, a.w};
#pragma unroll
        for (int q = 0; q < 4; ++q) {
          const float av_ = ak[q];
          const float4 b0 = bv0[q], b1 = bv1[q];
          acc[ii][0] += av_ * b0.x; acc[ii][1] += av_ * b0.y;
          acc[ii][2] += av_ * b0.z; acc[ii][3] += av_ * b0.w;
          acc[ii][4] += av_ * b1.x; acc[ii][5] += av_ * b1.y;
          acc[ii][6] += av_ * b1.z; acc[ii][7] += av_ * b1.w;
        }
      }
    }
    __syncthreads();
  }

  const int c0 = bn + tx * 4, c1 = bn + 64 + tx * 4;
  const float4 bs0 = *(const float4*)&bias[c0];
  const float4 bs1 = *(const float4*)&bias[c1];
#pragma unroll
  for (int ii = 0; ii < 8; ++ii) {
    const int r = bm + ty + 16 * ii;
    float4 o0, o1;
    o0.x = acc[ii][0] + bs0.x; o0.y = acc[ii][1] + bs0.y;
    o0.z = acc[ii][2] + bs0.z; o0.w = acc[ii][3] + bs0.w;
    o1.x = acc[ii][4] + bs1.x; o1.y = acc[ii][5] + bs1.y;
    o1.z = acc[ii][6] + bs1.z; o1.w = acc[ii][7] + bs1.w;
    if (ACT == 1) {
      o0.x = xla_tanh(o0.x); o0.y = xla_tanh(o0.y);
      o0.z = xla_tanh(o0.z); o0.w = xla_tanh(o0.w);
      o1.x = xla_tanh(o1.x); o1.y = xla_tanh(o1.y);
      o1.z = xla_tanh(o1.z); o1.w = xla_tanh(o1.w);
    }
    *(float4*)(C + (size_t)r * ldc + c0) = o0;
    *(float4*)(C + (size_t)r * ldc + c1) = o1;
  }
}

// ---------------- bf16x3 MFMA GEMM (round-6 proven body + XCD swizzle) ------
struct GemmArgs {
  const __bf16 *a0, *a1, *a2;
  const __bf16 *b0, *b1, *b2;
  const float* bias;
  float* c;
};

__global__ __launch_bounds__(256, 3) void gemm_mx3(
    GemmArgs g0, GemmArgs g1, int N) {
  __shared__ __attribute__((aligned(16))) __bf16 lds[6 * 4096];  // 48 KiB

  const GemmArgs g = blockIdx.z ? g1 : g0;
  const int tid = threadIdx.x;
  const int nwg = gridDim.x * gridDim.y;
  const int lin = blockIdx.y * gridDim.x + blockIdx.x;
  const int swz = (lin & 7) * (nwg >> 3) + (lin >> 3);
  const int bm = (swz / gridDim.x) * 128;
  const int bn = (swz % gridDim.x) * 128;
  const int lane = tid & 63;
  const int w  = tid >> 6;
  const int wm = w & 1;
  const int wn = w >> 1;
  const int l15 = lane & 15;
  const int kge = (lane >> 4) * 8;

  const int srow = tid >> 2;
  const int sge  = (tid & 3) * 8;
  const __bf16* tp[6];
  tp[0] = g.a0 + (size_t)(bm + srow) * 512 + sge;
  tp[1] = g.a1 + (size_t)(bm + srow) * 512 + sge;
  tp[2] = g.a2 + (size_t)(bm + srow) * 512 + sge;
  tp[3] = g.b0 + (size_t)(bn + srow) * 512 + sge;
  tp[4] = g.b1 + (size_t)(bn + srow) * 512 + sge;
  tp[5] = g.b2 + (size_t)(bn + srow) * 512 + sge;

  int aoff[4], boff[4];
#pragma unroll
  for (int i = 0; i < 4; ++i) {
    aoff[i] = (wm * 64 + i * 16 + l15) * 32 + kge;
    boff[i] = (wn * 64 + i * 16 + l15) * 32 + kge;
  }

  f32x4 acc[4][4] = {};

  for (int s = 0; s < 16; ++s) {
    const int k0 = s * 32;
#pragma unroll
    for (int p = 0; p < 6; ++p) {
      gl_lds16(tp[p] + k0,                    &lds[p * 4096 + w * 512]);
      gl_lds16(tp[p] + (size_t)64 * 512 + k0, &lds[p * 4096 + 2048 + w * 512]);
    }
    __syncthreads();

    bf16x8 Af[3][4];
#pragma unroll
    for (int mi = 0; mi < 4; ++mi) {
      Af[0][mi] = *(const bf16x8*)&lds[0 * 4096 + aoff[mi]];
      Af[1][mi] = *(const bf16x8*)&lds[1 * 4096 + aoff[mi]];
      Af[2][mi] = *(const bf16x8*)&lds[2 * 4096 + aoff[mi]];
    }
#pragma unroll
    for (int nj = 0; nj < 4; ++nj) {
      bf16x8 B0 = *(const bf16x8*)&lds[3 * 4096 + boff[nj]];
      bf16x8 B1 = *(const bf16x8*)&lds[4 * 4096 + boff[nj]];
      bf16x8 B2 = *(const bf16x8*)&lds[5 * 4096 + boff[nj]];
#pragma unroll
      for (int mi = 0; mi < 4; ++mi) {
        f32x4 c = acc[mi][nj];
        MFMA9(c, Af[0][mi], Af[1][mi], Af[2][mi], B0, B1, B2);
        acc[mi][nj] = c;
      }
    }
    __syncthreads();
  }

#pragma unroll
  for (int mi = 0; mi < 4; ++mi) {
    const int row0 = bm + wm * 64 + mi * 16 + (lane >> 4) * 4;
#pragma unroll
    for (int nj = 0; nj < 4; ++nj) {
      const int col = bn + wn * 64 + nj * 16 + l15;
      const float bv = g.bias[col];
      f32x4 v = acc[mi][nj];
#pragma unroll
      for (int r = 0; r < 4; ++r)
        g.c[(size_t)(row0 + r) * N + col] = v[r] + bv;
    }
  }
}

// ---------------- fused gh0-GEMM + gates0 (layer 0; proven round 9) ---------
__global__ __launch_bounds__(256, 2) void gemm_gru0(
    const __bf16* __restrict__ a0, const __bf16* __restrict__ a1,
    const __bf16* __restrict__ a2,
    const __bf16* __restrict__ wb0, const __bf16* __restrict__ wb1,
    const __bf16* __restrict__ wb2,
    const float* __restrict__ bias, const float* __restrict__ Eih0,
    const int* __restrict__ curTok,
    __bf16* __restrict__ q0, __bf16* __restrict__ q1,
    __bf16* __restrict__ q2) {
  __shared__ __attribute__((aligned(16))) __bf16 As[3][4096];  // 24 KiB
  __shared__ __attribute__((aligned(16))) __bf16 Bs[9][1024];  // 18 KiB

  const int tid = threadIdx.x;
  const int nwg = gridDim.x * gridDim.y;         // 512
  const int lin = blockIdx.y * gridDim.x + blockIdx.x;
  const int swz = (lin & 7) * (nwg >> 3) + (lin >> 3);
  const int bm = (swz / gridDim.x) * 128;
  const int bn = (swz % gridDim.x) * 32;
  const int lane = tid & 63;
  const int w  = tid >> 6;
  const int wm = w & 1;
  const int wn = w >> 1;
  const int l15 = lane & 15;
  const int kge = (lane >> 4) * 8;

  const int srow = tid >> 2;
  const int sge  = (tid & 3) * 8;
  const __bf16* tpA[3];
  tpA[0] = a0 + (size_t)(bm + srow) * 512 + sge;
  tpA[1] = a1 + (size_t)(bm + srow) * 512 + sge;
  tpA[2] = a2 + (size_t)(bm + srow) * 512 + sge;

  const int bcol = lane >> 2;
  const int bge  = (lane & 3) * 8;

  int aoff[4];
#pragma unroll
  for (int i = 0; i < 4; ++i)
    aoff[i] = (wm * 64 + i * 16 + l15) * 32 + kge;
  const int boff = (wn * 16 + l15) * 32 + kge;

  f32x4 acc[3][4] = {};   // [gate][mi]

  for (int s = 0; s < 16; ++s) {
    const int k0 = s * 32;
#pragma unroll
    for (int p = 0; p < 3; ++p) {
      gl_lds16(tpA[p] + k0,                    &As[p][w * 512]);
      gl_lds16(tpA[p] + (size_t)64 * 512 + k0, &As[p][2048 + w * 512]);
    }
    for (int qq = w; qq < 9; qq += 4) {
      const int gg = qq / 3, pp = qq - gg * 3;
      const __bf16* wp = (pp == 0) ? wb0 : (pp == 1) ? wb1 : wb2;
      const __bf16* src =
          wp + (size_t)(gg * 512 + bn + bcol) * 512 + bge + k0;
      gl_lds16(src,                     &Bs[qq][0]);
      gl_lds16(src + (size_t)16 * 512,  &Bs[qq][512]);
    }
    __syncthreads();

    bf16x8 Af[3][4];
#pragma unroll
    for (int mi = 0; mi < 4; ++mi) {
      Af[0][mi] = *(const bf16x8*)&As[0][aoff[mi]];
      Af[1][mi] = *(const bf16x8*)&As[1][aoff[mi]];
      Af[2][mi] = *(const bf16x8*)&As[2][aoff[mi]];
    }
#pragma unroll
    for (int gg = 0; gg < 3; ++gg) {
      bf16x8 B0 = *(const bf16x8*)&Bs[gg * 3 + 0][boff];
      bf16x8 B1 = *(const bf16x8*)&Bs[gg * 3 + 1][boff];
      bf16x8 B2 = *(const bf16x8*)&Bs[gg * 3 + 2][boff];
#pragma unroll
      for (int mi = 0; mi < 4; ++mi) {
        f32x4 c = acc[gg][mi];
        MFMA9(c, Af[0][mi], Af[1][mi], Af[2][mi], B0, B1, B2);
        acc[gg][mi] = c;
      }
    }
    __syncthreads();
  }

  const int col = bn + wn * 16 + l15;
  const float bvr = bias[col];
  const float bvz = bias[512 + col];
  const float bvn = bias[1024 + col];
#pragma unroll
  for (int mi = 0; mi < 4; ++mi) {
    const int row0 = bm + wm * 64 + mi * 16 + (lane >> 4) * 4;
#pragma unroll
    for (int rr = 0; rr < 4; ++rr) {
      const int row = row0 + rr;
      const int tok = curTok[row];
      const float* e = Eih0 + (size_t)tok * 1536;
      const size_t idx = (size_t)row * 512 + col;
      float hold = __fadd_rn(__fadd_rn((float)a0[idx], (float)a1[idx]),
                             (float)a2[idx]);
      float hnew = gru_h(e[col], e[512 + col], e[1024 + col],
                         acc[0][mi][rr] + bvr, acc[1][mi][rr] + bvz,
                         acc[2][mi][rr] + bvn, hold);
      __bf16 s0, s1, s2;
      split3(hnew, s0, s1, s2);
      q0[idx] = s0; q1[idx] = s1; q2[idx] = s2;
    }
  }
}

// ---------------- fused layer-1: gi1+gh1 GEMMs + gates1 (PING-PONG h1) ------
// Round-10 bug: in-place h1 update raced (same-bm blocks with different bn
// write col-slices other blocks still read as gh1 A-operand). Fix: read
// hi* planes, write ho* planes (ping-pong per step). Math bit-identical.
__global__ __launch_bounds__(256, 2) void gemm_gru1(
    const __bf16* __restrict__ x0, const __bf16* __restrict__ x1,
    const __bf16* __restrict__ x2,        // h0' planes (gi A operand)
    const __bf16* __restrict__ wi0, const __bf16* __restrict__ wi1,
    const __bf16* __restrict__ wi2,       // w_ih1 planes
    const __bf16* __restrict__ wh0, const __bf16* __restrict__ wh1,
    const __bf16* __restrict__ wh2,       // w_hh1 planes
    const float* __restrict__ bias_i, const float* __restrict__ bias_h,
    const __bf16* __restrict__ hi0, const __bf16* __restrict__ hi1,
    const __bf16* __restrict__ hi2,       // h1 IN planes (gh A operand + hold)
    __bf16* __restrict__ ho0, __bf16* __restrict__ ho1,
    __bf16* __restrict__ ho2) {           // h1 OUT planes
  __shared__ __attribute__((aligned(16))) __bf16 As[6][2048];   // 24 KiB
  __shared__ __attribute__((aligned(16))) __bf16 Bs[18][1024];  // 36 KiB

  const int tid = threadIdx.x;
  const int nwg = gridDim.x * gridDim.y;         // 1024
  const int lin = blockIdx.y * gridDim.x + blockIdx.x;
  const int swz = (lin & 7) * (nwg >> 3) + (lin >> 3);
  const int bm = (swz / gridDim.x) * 64;
  const int bn = (swz % gridDim.x) * 32;
  const int lane = tid & 63;
  const int w  = tid >> 6;
  const int wm = w & 1;                // 32-row half
  const int wn = w >> 1;               // 16-col half
  const int l15 = lane & 15;
  const int kge = (lane >> 4) * 8;

  const int srow = tid >> 2;
  const int sge  = (tid & 3) * 8;
  const __bf16* tpA[6];
  tpA[0] = x0 + (size_t)(bm + srow) * 512 + sge;
  tpA[1] = x1 + (size_t)(bm + srow) * 512 + sge;
  tpA[2] = x2 + (size_t)(bm + srow) * 512 + sge;
  tpA[3] = hi0 + (size_t)(bm + srow) * 512 + sge;
  tpA[4] = hi1 + (size_t)(bm + srow) * 512 + sge;
  tpA[5] = hi2 + (size_t)(bm + srow) * 512 + sge;

  const int bcol = lane >> 2;          // 16 cols per wave-issue
  const int bge  = (lane & 3) * 8;

  int aoff[2];
#pragma unroll
  for (int i = 0; i < 2; ++i)
    aoff[i] = (wm * 32 + i * 16 + l15) * 32 + kge;
  const int boff = (wn * 16 + l15) * 32 + kge;

  f32x4 acci[3][2] = {};   // gi accumulators [gate][mi]
  f32x4 acch[3][2] = {};   // gh accumulators

  const __bf16* wis[3] = {wi0, wi1, wi2};
  const __bf16* whs[3] = {wh0, wh1, wh2};

  for (int s = 0; s < 16; ++s) {
    const int k0 = s * 32;
#pragma unroll
    for (int p = 0; p < 6; ++p)
      gl_lds16(tpA[p] + k0, &As[p][w * 512]);
    for (int qq = w; qq < 18; qq += 4) {   // qq = wset*9 + gg*3 + pp
      const int wset = qq / 9;
      const int gg = (qq - wset * 9) / 3, pp = qq - wset * 9 - gg * 3;
      const __bf16* wp = wset ? whs[pp] : wis[pp];
      const __bf16* src = wp + (size_t)(gg * 512 + bn + bcol) * 512 + bge + k0;
      gl_lds16(src,                    &Bs[qq][0]);
      gl_lds16(src + (size_t)16 * 512, &Bs[qq][512]);
    }
    __syncthreads();

    bf16x8 Xf[3][2], Hf[3][2];
#pragma unroll
    for (int mi = 0; mi < 2; ++mi) {
      Xf[0][mi] = *(const bf16x8*)&As[0][aoff[mi]];
      Xf[1][mi] = *(const bf16x8*)&As[1][aoff[mi]];
      Xf[2][mi] = *(const bf16x8*)&As[2][aoff[mi]];
      Hf[0][mi] = *(const bf16x8*)&As[3][aoff[mi]];
      Hf[1][mi] = *(const bf16x8*)&As[4][aoff[mi]];
      Hf[2][mi] = *(const bf16x8*)&As[5][aoff[mi]];
    }
#pragma unroll
    for (int gg = 0; gg < 3; ++gg) {
      bf16x8 Bi0 = *(const bf16x8*)&Bs[gg * 3 + 0][boff];
      bf16x8 Bi1 = *(const bf16x8*)&Bs[gg * 3 + 1][boff];
      bf16x8 Bi2 = *(const bf16x8*)&Bs[gg * 3 + 2][boff];
      bf16x8 Bh0 = *(const bf16x8*)&Bs[9 + gg * 3 + 0][boff];
      bf16x8 Bh1 = *(const bf16x8*)&Bs[9 + gg * 3 + 1][boff];
      bf16x8 Bh2 = *(const bf16x8*)&Bs[9 + gg * 3 + 2][boff];
#pragma unroll
      for (int mi = 0; mi < 2; ++mi) {
        f32x4 ci = acci[gg][mi];
        MFMA9(ci, Xf[0][mi], Xf[1][mi], Xf[2][mi], Bi0, Bi1, Bi2);
        acci[gg][mi] = ci;
        f32x4 ch = acch[gg][mi];
        MFMA9(ch, Hf[0][mi], Hf[1][mi], Hf[2][mi], Bh0, Bh1, Bh2);
        acch[gg][mi] = ch;
      }
    }
    __syncthreads();
  }

  const int col = bn + wn * 16 + l15;
  const float bir = bias_i[col];
  const float biz = bias_i[512 + col];
  const float bin = bias_i[1024 + col];
  const float bhr = bias_h[col];
  const float bhz = bias_h[512 + col];
  const float bhn = bias_h[1024 + col];
#pragma unroll
  for (int mi = 0; mi < 2; ++mi) {
    const int row0 = bm + wm * 32 + mi * 16 + (lane >> 4) * 4;
#pragma unroll
    for (int rr = 0; rr < 4; ++rr) {
      const int row = row0 + rr;
      const size_t idx = (size_t)row * 512 + col;
      float hold = __fadd_rn(__fadd_rn((float)hi0[idx], (float)hi1[idx]),
                             (float)hi2[idx]);
      float hnew = gru_h(acci[0][mi][rr] + bir, acci[1][mi][rr] + biz,
                         acci[2][mi][rr] + bin,
                         acch[0][mi][rr] + bhr, acch[1][mi][rr] + bhz,
                         acch[2][mi][rr] + bhn, hold);
      __bf16 s0, s1, s2;
      split3(hnew, s0, s1, s2);
      ho0[idx] = s0; ho1[idx] = s1; ho2[idx] = s2;
    }
  }
}

// ---------------- splitters / transpose -------------------------------------
__global__ __launch_bounds__(256) void k_split(
    const float* __restrict__ in, __bf16* __restrict__ p0,
    __bf16* __restrict__ p1, __bf16* __restrict__ p2, int total) {
  int i = blockIdx.x * 256 + threadIdx.x;
  if (i >= total) return;
  __bf16 a0, a1, a2;
  split3(in[i], a0, a1, a2);
  p0[i] = a0; p1[i] = a1; p2[i] = a2;
}

__global__ __launch_bounds__(256) void k_transpose(
    const float* __restrict__ in, float* __restrict__ out, int R, int C) {
  __shared__ float tile[32][33];
  int c0 = blockIdx.x * 32, r0 = blockIdx.y * 32;
  int x = threadIdx.x, y0 = threadIdx.y;
  for (int i = y0; i < 32; i += 8) {
    int r = r0 + i, c = c0 + x;
    tile[i][x] = (r < R && c < C) ? in[(size_t)r * C + c] : 0.0f;
  }
  __syncthreads();
  for (int i = y0; i < 32; i += 8) {
    int orow = c0 + i, oc = r0 + x;
    if (orow < C && oc < R) out[(size_t)orow * R + oc] = tile[x][i];
  }
}

// ---------------- sampling ---------------------------------------------------
__global__ __launch_bounds__(256) void k_sample(
    const float* __restrict__ logits, int* __restrict__ cur,
    int* __restrict__ finished, int* __restrict__ outTok,
    int t, uint32_t sk0, uint32_t sk1) {
  const int row = blockIdx.x;
  const int tid = threadIdx.x;
  __shared__ float sl[kVoc];
  __shared__ uint32_t skeys[kVoc];
  __shared__ int   redi[4];
  __shared__ float redf[4];
  __shared__ int   redix[4];

  const float* lp = logits + (size_t)row * kVoc;
  for (int c = tid; c < kVoc; c += 256) {
    float v = lp[c];
    if (c == kBos || c == kPad) v = kNeg;
    if (c == kEos && t < 1 + kEffMin) v = kNeg;
    sl[c] = v;
    uint32_t u = __float_as_uint(v);
    skeys[c] = u ^ ((u >> 31) ? 0xFFFFFFFFu : 0x80000000u);
  }
  __syncthreads();

  uint32_t prefix = 0u;
  for (int b = 31; b >= 0; --b) {
    uint32_t trial = prefix | (1u << b);
    int cnt = 0;
    for (int c = tid; c < kVoc; c += 256) cnt += (skeys[c] >= trial) ? 1 : 0;
#pragma unroll
    for (int off = 32; off; off >>= 1) cnt += __shfl_down(cnt, off, 64);
    __syncthreads();
    if ((tid & 63) == 0) redi[tid >> 6] = cnt;
    __syncthreads();
    int total = redi[0] + redi[1] + redi[2] + redi[3];
    if (total >= kTopK) prefix = trial;
  }

  float best = -3.4e38f; int bidx = kVoc;
  for (int c = tid; c < kVoc; c += 256) {
    if (skeys[c] >= prefix) {
      uint32_t idx = (uint32_t)row * (uint32_t)kVoc + (uint32_t)c;
      uint32_t w1, w2, bits;
#if PARTITIONABLE
      tf2x32(sk0, sk1, 0u, idx, w1, w2);
      bits = w1 ^ w2;
#else
      const uint32_t HH = (uint32_t)((uint64_t)kBatch * kVoc / 2);
      if (idx < HH) { tf2x32(sk0, sk1, idx, idx + HH, w1, w2); bits = w1; }
      else          { tf2x32(sk0, sk1, idx - HH, idx, w1, w2); bits = w2; }
#endif
      uint32_t fb = (bits >> 9) | 0x3f800000u;
      float uf = __fsub_rn(__uint_as_float(fb), 1.0f);
      if (uf == 0.0f) uf = kTiny;
      float g = -logf(-logf(uf));
      float tot = __fadd_rn(g, sl[c]);
      if (tot > best || (tot == best && c < bidx)) { best = tot; bidx = c; }
    }
  }
#pragma unroll
  for (int off = 32; off; off >>= 1) {
    float ov = __shfl_down(best, off, 64);
    int   oi = __shfl_down(bidx, off, 64);
    if (ov > best || (ov == best && oi < bidx)) { best = ov; bidx = oi; }
  }
  if ((tid & 63) == 0) { redf[tid >> 6] = best; redix[tid >> 6] = bidx; }
  __syncthreads();
  if (tid == 0) {
    for (int w = 1; w < 4; ++w) {
      if (redf[w] > best || (redf[w] == best && redix[w] < bidx)) {
        best = redf[w]; bidx = redix[w];
      }
    }
    int fin = finished[row];
    int nxt = fin ? kPad : bidx;
    outTok[(size_t)row * kMaxLen + t] = nxt;
    cur[row] = nxt;
    finished[row] = fin | (nxt == kEos);
  }
}

__global__ __launch_bounds__(256) void k_init(int* cur, int* finished, int* outTok) {
  int i = blockIdx.x * 256 + threadIdx.x;
  if (i < kBatch) {
    cur[i] = kBos;
    finished[i] = 0;
    outTok[(size_t)i * kMaxLen] = kBos;
  }
}

extern "C" void kernel_launch(void* const* d_in, const int* in_sizes, int n_in,
                              void* d_out, int out_size, void* d_ws, size_t ws_size,
                              hipStream_t stream) {
  (void)in_sizes; (void)n_in; (void)out_size; (void)ws_size;
  const float* z      = (const float*)d_in[0];
  const float* embed  = (const float*)d_in[1];
  const float* w_lh   = (const float*)d_in[2];
  const float* b_lh   = (const float*)d_in[3];
  const float* w_ih0  = (const float*)d_in[4];
  const float* w_hh0  = (const float*)d_in[5];
  const float* b_ih0  = (const float*)d_in[6];
  const float* b_hh0  = (const float*)d_in[7];
  const float* w_ih1  = (const float*)d_in[8];
  const float* w_hh1  = (const float*)d_in[9];
  const float* b_ih1  = (const float*)d_in[10];
  const float* b_hh1  = (const float*)d_in[11];
  const float* w_out  = (const float*)d_in[12];
  const float* b_out  = (const float*)d_in[13];
  int* out = (int*)d_out;

  // ---- workspace: round-9 layout (121.2 MB proven); hs1B aliases gi1 tail
  // (gi1 floats [2M..5.1M) = beyond logits' reach, dead otherwise) ----
  char* base = (char*)d_ws;
  int* curTok   = (int*)base;
  int* finished = curTok + kBatch;
  __bf16* q = (__bf16*)(base + 32768);
  __bf16* whh0[3]; __bf16* wih1[3]; __bf16* whh1[3]; __bf16* wout[3];
  for (int i = 0; i < 3; ++i) { whh0[i] = q; q += (size_t)1536 * 512; }
  for (int i = 0; i < 3; ++i) { wih1[i] = q; q += (size_t)1536 * 512; }
  for (int i = 0; i < 3; ++i) { whh1[i] = q; q += (size_t)1536 * 512; }
  for (int i = 0; i < 3; ++i) { wout[i] = q; q += (size_t)2048 * 512; }
  __bf16* hs0A[3]; __bf16* hs1A[3];
  for (int i = 0; i < 3; ++i) { hs0A[i] = q; q += (size_t)kBatch * kHid; }
  for (int i = 0; i < 3; ++i) { hs1A[i] = q; q += (size_t)kBatch * kHid; }
  float* f = (float*)q;
  float* Eih0 = f; f += (size_t)kVoc * 1536;
  float* ghA  = f; f += (size_t)kBatch * 1536;
  float* gi1  = f; f += (size_t)kBatch * 1536;
  float* logits = ghA;                       // spans ghA + first 2M floats of gi1
  float* wt_ih0 = ghA;                       // init-only aliases
  float* wt_lh  = ghA + (size_t)128 * 1536;
  float* h0tmp  = gi1;
  float* h1tmp  = gi1 + (size_t)kBatch * kHid;
  __bf16* hs0B[3];
  { __bf16* hb = (__bf16*)f;
    for (int i = 0; i < 3; ++i) { hs0B[i] = hb; hb += (size_t)kBatch * kHid; } }
  __bf16* hs1B[3];
  { // gi1 tail beyond logits: gi1 + 2,097,152 floats (logits end). 12.6 MB free.
    __bf16* hb = (__bf16*)(gi1 + (size_t)kBatch * kHid);  // = logits end
    for (int i = 0; i < 3; ++i) { hs1B[i] = hb; hb += (size_t)kBatch * kHid; } }

  dim3 blk(256);
  dim3 tblk(32, 8);

  // ---- one-time setup ----
  k_transpose<<<dim3(4, 48), tblk, 0, stream>>>(w_ih0, wt_ih0, 1536, 128);
  k_transpose<<<dim3(4, 32), tblk, 0, stream>>>(w_lh,  wt_lh,  1024, 128);
  k_split<<<dim3(1536 * 512 / 256), blk, 0, stream>>>(w_hh0, whh0[0], whh0[1], whh0[2], 1536 * 512);
  k_split<<<dim3(1536 * 512 / 256), blk, 0, stream>>>(w_ih1, wih1[0], wih1[1], wih1[2], 1536 * 512);
  k_split<<<dim3(1536 * 512 / 256), blk, 0, stream>>>(w_hh1, whh1[0], whh1[1], whh1[2], 1536 * 512);
  k_split<<<dim3(2048 * 512 / 256), blk, 0, stream>>>(w_out, wout[0], wout[1], wout[2], 2048 * 512);

  gemm2<0><<<dim3(12, 16, 1), blk, 0, stream>>>(
      embed, wt_ih0, b_ih0, Eih0, embed, wt_ih0, b_ih0, Eih0,
      kEmb, 1536, 1536, kEmb);
  gemm2<1><<<dim3(4, 32, 2), blk, 0, stream>>>(
      z, wt_lh,       b_lh,       h0tmp,
      z, wt_lh + 512, b_lh + 512, h1tmp,
      kEmb, 1024, kHid, kEmb);
  k_split<<<dim3(kBatch * kHid / 256), blk, 0, stream>>>(h0tmp, hs0A[0], hs0A[1], hs0A[2], kBatch * kHid);
  k_split<<<dim3(kBatch * kHid / 256), blk, 0, stream>>>(h1tmp, hs1A[0], hs1A[1], hs1A[2], kBatch * kHid);
  k_init<<<dim3((kBatch + 255) / 256), blk, 0, stream>>>(curTok, finished, out);

  uint32_t key0 = 0u, key1 = 1u;   // jax.random.key(1)
  for (int t = 1; t < kMaxLen; ++t) {
    uint32_t nk0, nk1, s0, s1;
#if PARTITIONABLE
    tf2x32(key0, key1, 0u, 0u, nk0, nk1);
    tf2x32(key0, key1, 0u, 1u, s0, s1);
#else
    uint32_t a0, b0w, a1, b1w;
    tf2x32(key0, key1, 0u, 2u, a0, b0w);
    tf2x32(key0, key1, 1u, 3u, a1, b1w);
    nk0 = a0; nk1 = a1; s0 = b0w; s1 = b1w;
#endif
    __bf16** h0in  = (t & 1) ? hs0A : hs0B;
    __bf16** h0out = (t & 1) ? hs0B : hs0A;
    __bf16** h1in  = (t & 1) ? hs1A : hs1B;
    __bf16** h1out = (t & 1) ? hs1B : hs1A;

    // layer 0: fused gh0-GEMM + gates (ping-pong h0 planes)
    gemm_gru0<<<dim3(16, 32), blk, 0, stream>>>(
        h0in[0], h0in[1], h0in[2], whh0[0], whh0[1], whh0[2],
        b_hh0, Eih0, curTok, h0out[0], h0out[1], h0out[2]);

    // layer 1: fused gi1+gh1 GEMMs + gates (ping-pong h1 planes)
    gemm_gru1<<<dim3(16, 64), blk, 0, stream>>>(
        h0out[0], h0out[1], h0out[2],
        wih1[0], wih1[1], wih1[2],
        whh1[0], whh1[1], whh1[2],
        b_ih1, b_hh1,
        h1in[0], h1in[1], h1in[2],
        h1out[0], h1out[1], h1out[2]);

    // logits + sample
    GemmArgs gla{h1out[0], h1out[1], h1out[2], wout[0], wout[1], wout[2], b_out, logits};
    gemm_mx3<<<dim3(16, 32, 1), blk, 0, stream>>>(gla, gla, 2048);
    k_sample<<<dim3(kBatch), blk, 0, stream>>>(logits, curTok, finished, out, t, s0, s1);

    key0 = nk0; key1 = nk1;
  }
}

// Round 12
// 16299.751 us; speedup vs baseline: 1.2152x; 1.2152x over previous
//
#include <hip/hip_runtime.h>
#include <cstdint>
#include <cstddef>

#ifndef PARTITIONABLE
#define PARTITIONABLE 1
#endif

namespace {
constexpr int kBatch  = 4096;
constexpr int kEmb    = 128;
constexpr int kHid    = 512;
constexpr int kVoc    = 2048;
constexpr int kMaxLen = 64;
constexpr int kTopK   = 40;
constexpr int kBos = 1, kEos = 2, kPad = 0;
constexpr int kEffMin = 20;
constexpr float kNeg  = -1.0e9f;
constexpr float kTiny = 1.17549435082228751e-38f;
}

typedef __bf16 bf16x8 __attribute__((ext_vector_type(8)));
typedef float  f32x4  __attribute__((ext_vector_type(4)));

__host__ __device__ inline void tf2x32(uint32_t k0, uint32_t k1,
                                       uint32_t x0, uint32_t x1,
                                       uint32_t& o0, uint32_t& o1) {
  uint32_t ks0 = k0, ks1 = k1, ks2 = k0 ^ k1 ^ 0x1BD11BDAu;
  x0 += ks0; x1 += ks1;
#define TFR(r) { x0 += x1; x1 = (x1 << (r)) | (x1 >> (32 - (r))); x1 ^= x0; }
  TFR(13) TFR(15) TFR(26) TFR(6)   x0 += ks1; x1 += ks2 + 1u;
  TFR(17) TFR(29) TFR(16) TFR(24)  x0 += ks2; x1 += ks0 + 2u;
  TFR(13) TFR(15) TFR(26) TFR(6)   x0 += ks0; x1 += ks1 + 3u;
  TFR(17) TFR(29) TFR(16) TFR(24)  x0 += ks1; x1 += ks2 + 4u;
  TFR(13) TFR(15) TFR(26) TFR(6)   x0 += ks2; x1 += ks0 + 5u;
#undef TFR
  o0 = x0; o1 = x1;
}

__device__ __forceinline__ float xla_tanh(float x) {
  float ax = fabsf(x);
  float xc = fminf(fmaxf(x, -9.0f), 9.0f);
  float x2 = __fmul_rn(xc, xc);
  float num = -2.76076847742355e-16f;
  num = __fadd_rn(__fmul_rn(x2, num), 2.00018790482477e-13f);
  num = __fadd_rn(__fmul_rn(x2, num), -8.60467152213735e-11f);
  num = __fadd_rn(__fmul_rn(x2, num), 5.12229709037114e-08f);
  num = __fadd_rn(__fmul_rn(x2, num), 1.48572235717979e-05f);
  num = __fadd_rn(__fmul_rn(x2, num), 6.37261928875436e-04f);
  num = __fadd_rn(__fmul_rn(x2, num), 4.89352455891786e-03f);
  num = __fmul_rn(xc, num);
  float den = 1.19825839466702e-06f;
  den = __fadd_rn(__fmul_rn(x2, den), 1.18534705686654e-04f);
  den = __fadd_rn(__fmul_rn(x2, den), 2.26843463243900e-03f);
  den = __fadd_rn(__fmul_rn(x2, den), 4.89352518554385e-03f);
  return (ax < 4.0e-04f) ? x : __fdiv_rn(num, den);
}

__device__ __forceinline__ float xla_sigmoid(float x) {
  return __fdiv_rn(1.0f, __fadd_rn(1.0f, expf(-x)));
}

__device__ __forceinline__ void gl_lds16(const void* g, void* l) {
  __builtin_amdgcn_global_load_lds(
      (const __attribute__((address_space(1))) void*)g,
      (__attribute__((address_space(3))) void*)l, 16, 0, 0);
}

__device__ __forceinline__ void split3(float a, __bf16& a0, __bf16& a1, __bf16& a2) {
  a0 = (__bf16)a;
  float r1 = __fsub_rn(a, (float)a0);
  a1 = (__bf16)r1;
  float r2 = __fsub_rn(r1, (float)a1);
  a2 = (__bf16)r2;   // exact: 3x8 mantissa bits cover f32's 24
}

__device__ __forceinline__ float gru_h(float gir, float giz, float gin,
                                       float ghr, float ghz, float ghn,
                                       float hold) {
  float r = xla_sigmoid(__fadd_rn(gir, ghr));
  float u = xla_sigmoid(__fadd_rn(giz, ghz));
  float n = xla_tanh(__fadd_rn(gin, __fmul_rn(r, ghn)));
  float t1 = __fmul_rn(__fsub_rn(1.0f, u), n);
  float t2 = __fmul_rn(u, hold);
  return __fadd_rn(t1, t2);
}

#define MFMA9(c, A0_, A1_, A2_, B0_, B1_, B2_) do {                          \
    c = __builtin_amdgcn_mfma_f32_16x16x32_bf16(A2_, B2_, c, 0, 0, 0);       \
    c = __builtin_amdgcn_mfma_f32_16x16x32_bf16(A2_, B1_, c, 0, 0, 0);       \
    c = __builtin_amdgcn_mfma_f32_16x16x32_bf16(A1_, B2_, c, 0, 0, 0);       \
    c = __builtin_amdgcn_mfma_f32_16x16x32_bf16(A2_, B0_, c, 0, 0, 0);       \
    c = __builtin_amdgcn_mfma_f32_16x16x32_bf16(A1_, B1_, c, 0, 0, 0);       \
    c = __builtin_amdgcn_mfma_f32_16x16x32_bf16(A0_, B2_, c, 0, 0, 0);       \
    c = __builtin_amdgcn_mfma_f32_16x16x32_bf16(A1_, B0_, c, 0, 0, 0);       \
    c = __builtin_amdgcn_mfma_f32_16x16x32_bf16(A0_, B1_, c, 0, 0, 0);       \
    c = __builtin_amdgcn_mfma_f32_16x16x32_bf16(A0_, B0_, c, 0, 0, 0);       \
  } while (0)

// ---------------- f32 vector GEMM (init only; proven rounds 1-2) ------------
template <int ACT>
__global__ __launch_bounds__(256) void gemm2(
    const float* __restrict__ A0, const float* __restrict__ B0,
    const float* __restrict__ bias0, float* __restrict__ C0,
    const float* __restrict__ A1, const float* __restrict__ B1,
    const float* __restrict__ bias1, float* __restrict__ C1,
    int lda, int ldb, int ldc, int K) {
  __shared__ __attribute__((aligned(16))) float As[2][128 * 16];
  __shared__ __attribute__((aligned(16))) float Bs[2][16 * 128];

  const float* A    = blockIdx.z ? A1 : A0;
  const float* Bt   = blockIdx.z ? B1 : B0;
  const float* bias = blockIdx.z ? bias1 : bias0;
  float*       C    = blockIdx.z ? C1 : C0;

  const int tid = threadIdx.x;
  const int w = tid >> 6, l = tid & 63;
  const int bm = blockIdx.y * 128;
  const int bn = blockIdx.x * 128;
  const int tx = tid & 15, ty = tid >> 4;
  const int t3 = ty & 3;

  const int arow  = w * 16 + (l >> 2);
  const int agran = (l & 3) ^ ((l >> 2) & 3);
  const float* pA = A + (size_t)(bm + arow) * lda + agran * 4;
  const int bk = w * 2 + (l >> 5);
  const int bnc = (l & 31) * 4;
  const float* pB = Bt + (size_t)bk * ldb + bn + bnc;

  float acc[8][8];
#pragma unroll
  for (int i = 0; i < 8; ++i)
#pragma unroll
    for (int j = 0; j < 8; ++j) acc[i][j] = 0.0f;

  const int nt = K >> 4;
  gl_lds16(pA,            &As[0][w * 256]);
  gl_lds16(pA + 64 * lda, &As[0][(4 + w) * 256]);
  gl_lds16(pB,            &Bs[0][w * 256]);
  gl_lds16(pB + (size_t)8 * ldb, &Bs[0][(4 + w) * 256]);
  __syncthreads();

  for (int t = 0; t < nt; ++t) {
    const int cur = t & 1;
    if (t + 1 < nt) {
      const float* qA = pA + (t + 1) * 16;
      const float* qB = pB + (size_t)(t + 1) * 16 * ldb;
      gl_lds16(qA,            &As[cur ^ 1][w * 256]);
      gl_lds16(qA + 64 * lda, &As[cur ^ 1][(4 + w) * 256]);
      gl_lds16(qB,            &Bs[cur ^ 1][w * 256]);
      gl_lds16(qB + (size_t)8 * ldb, &Bs[cur ^ 1][(4 + w) * 256]);
    }
    const float* as = As[cur];
    const float* bs = Bs[cur];
#pragma unroll
    for (int g = 0; g < 4; ++g) {
      float4 bv0[4], bv1[4];
#pragma unroll
      for (int q = 0; q < 4; ++q) {
        bv0[q] = *(const float4*)&bs[(g * 4 + q) * 128 + tx * 4];
        bv1[q] = *(const float4*)&bs[(g * 4 + q) * 128 + 64 + tx * 4];
      }
#pragma unroll
      for (int ii = 0; ii < 8; ++ii) {
        float4 a = *(const float4*)&as[(ty + 16 * ii) * 16 + ((g ^ t3) * 4)];
        float ak[4] = {a.x, a.y, a.z, a.w};
#pragma unroll
        for (int q = 0; q < 4; ++q) {
          const float av_ = ak[q];
          const float4 b0 = bv0[q], b1 = bv1[q];
          acc[ii][0] += av_ * b0.x; acc[ii][1] += av_ * b0.y;
          acc[ii][2] += av_ * b0.z; acc[ii][3] += av_ * b0.w;
          acc[ii][4] += av_ * b1.x; acc[ii][5] += av_ * b1.y;
          acc[ii][6] += av_ * b1.z; acc[ii][7] += av_ * b1.w;
        }
      }
    }
    __syncthreads();
  }

  const int c0 = bn + tx * 4, c1 = bn + 64 + tx * 4;
  const float4 bs0 = *(const float4*)&bias[c0];
  const float4 bs1 = *(const float4*)&bias[c1];
#pragma unroll
  for (int ii = 0; ii < 8; ++ii) {
    const int r = bm + ty + 16 * ii;
    float4 o0, o1;
    o0.x = acc[ii][0] + bs0.x; o0.y = acc[ii][1] + bs0.y;
    o0.z = acc[ii][2] + bs0.z; o0.w = acc[ii][3] + bs0.w;
    o1.x = acc[ii][4] + bs1.x; o1.y = acc[ii][5] + bs1.y;
    o1.z = acc[ii][6] + bs1.z; o1.w = acc[ii][7] + bs1.w;
    if (ACT == 1) {
      o0.x = xla_tanh(o0.x); o0.y = xla_tanh(o0.y);
      o0.z = xla_tanh(o0.z); o0.w = xla_tanh(o0.w);
      o1.x = xla_tanh(o1.x); o1.y = xla_tanh(o1.y);
      o1.z = xla_tanh(o1.z); o1.w = xla_tanh(o1.w);
    }
    *(float4*)(C + (size_t)r * ldc + c0) = o0;
    *(float4*)(C + (size_t)r * ldc + c1) = o1;
  }
}

// ---------------- bf16x3 MFMA GEMM (round-6 proven body + XCD swizzle) ------
struct GemmArgs {
  const __bf16 *a0, *a1, *a2;
  const __bf16 *b0, *b1, *b2;
  const float* bias;
  float* c;
};

__global__ __launch_bounds__(256, 3) void gemm_mx3(
    GemmArgs g0, GemmArgs g1, int N) {
  __shared__ __attribute__((aligned(16))) __bf16 lds[6 * 4096];  // 48 KiB

  const GemmArgs g = blockIdx.z ? g1 : g0;
  const int tid = threadIdx.x;
  const int nwg = gridDim.x * gridDim.y;
  const int lin = blockIdx.y * gridDim.x + blockIdx.x;
  const int swz = (lin & 7) * (nwg >> 3) + (lin >> 3);
  const int bm = (swz / gridDim.x) * 128;
  const int bn = (swz % gridDim.x) * 128;
  const int lane = tid & 63;
  const int w  = tid >> 6;
  const int wm = w & 1;
  const int wn = w >> 1;
  const int l15 = lane & 15;
  const int kge = (lane >> 4) * 8;

  const int srow = tid >> 2;
  const int sge  = (tid & 3) * 8;
  const __bf16* tp[6];
  tp[0] = g.a0 + (size_t)(bm + srow) * 512 + sge;
  tp[1] = g.a1 + (size_t)(bm + srow) * 512 + sge;
  tp[2] = g.a2 + (size_t)(bm + srow) * 512 + sge;
  tp[3] = g.b0 + (size_t)(bn + srow) * 512 + sge;
  tp[4] = g.b1 + (size_t)(bn + srow) * 512 + sge;
  tp[5] = g.b2 + (size_t)(bn + srow) * 512 + sge;

  int aoff[4], boff[4];
#pragma unroll
  for (int i = 0; i < 4; ++i) {
    aoff[i] = (wm * 64 + i * 16 + l15) * 32 + kge;
    boff[i] = (wn * 64 + i * 16 + l15) * 32 + kge;
  }

  f32x4 acc[4][4] = {};

  for (int s = 0; s < 16; ++s) {
    const int k0 = s * 32;
#pragma unroll
    for (int p = 0; p < 6; ++p) {
      gl_lds16(tp[p] + k0,                    &lds[p * 4096 + w * 512]);
      gl_lds16(tp[p] + (size_t)64 * 512 + k0, &lds[p * 4096 + 2048 + w * 512]);
    }
    __syncthreads();

    bf16x8 Af[3][4];
#pragma unroll
    for (int mi = 0; mi < 4; ++mi) {
      Af[0][mi] = *(const bf16x8*)&lds[0 * 4096 + aoff[mi]];
      Af[1][mi] = *(const bf16x8*)&lds[1 * 4096 + aoff[mi]];
      Af[2][mi] = *(const bf16x8*)&lds[2 * 4096 + aoff[mi]];
    }
#pragma unroll
    for (int nj = 0; nj < 4; ++nj) {
      bf16x8 B0 = *(const bf16x8*)&lds[3 * 4096 + boff[nj]];
      bf16x8 B1 = *(const bf16x8*)&lds[4 * 4096 + boff[nj]];
      bf16x8 B2 = *(const bf16x8*)&lds[5 * 4096 + boff[nj]];
#pragma unroll
      for (int mi = 0; mi < 4; ++mi) {
        f32x4 c = acc[mi][nj];
        MFMA9(c, Af[0][mi], Af[1][mi], Af[2][mi], B0, B1, B2);
        acc[mi][nj] = c;
      }
    }
    __syncthreads();
  }

#pragma unroll
  for (int mi = 0; mi < 4; ++mi) {
    const int row0 = bm + wm * 64 + mi * 16 + (lane >> 4) * 4;
#pragma unroll
    for (int nj = 0; nj < 4; ++nj) {
      const int col = bn + wn * 64 + nj * 16 + l15;
      const float bv = g.bias[col];
      f32x4 v = acc[mi][nj];
#pragma unroll
      for (int r = 0; r < 4; ++r)
        g.c[(size_t)(row0 + r) * N + col] = v[r] + bv;
    }
  }
}

// ---------------- fused gh0-GEMM + gates0 (layer 0; proven round 9) ---------
__global__ __launch_bounds__(256, 2) void gemm_gru0(
    const __bf16* __restrict__ a0, const __bf16* __restrict__ a1,
    const __bf16* __restrict__ a2,
    const __bf16* __restrict__ wb0, const __bf16* __restrict__ wb1,
    const __bf16* __restrict__ wb2,
    const float* __restrict__ bias, const float* __restrict__ Eih0,
    const int* __restrict__ curTok,
    __bf16* __restrict__ q0, __bf16* __restrict__ q1,
    __bf16* __restrict__ q2) {
  __shared__ __attribute__((aligned(16))) __bf16 As[3][4096];  // 24 KiB
  __shared__ __attribute__((aligned(16))) __bf16 Bs[9][1024];  // 18 KiB

  const int tid = threadIdx.x;
  const int nwg = gridDim.x * gridDim.y;         // 512
  const int lin = blockIdx.y * gridDim.x + blockIdx.x;
  const int swz = (lin & 7) * (nwg >> 3) + (lin >> 3);
  const int bm = (swz / gridDim.x) * 128;
  const int bn = (swz % gridDim.x) * 32;
  const int lane = tid & 63;
  const int w  = tid >> 6;
  const int wm = w & 1;
  const int wn = w >> 1;
  const int l15 = lane & 15;
  const int kge = (lane >> 4) * 8;

  const int srow = tid >> 2;
  const int sge  = (tid & 3) * 8;
  const __bf16* tpA[3];
  tpA[0] = a0 + (size_t)(bm + srow) * 512 + sge;
  tpA[1] = a1 + (size_t)(bm + srow) * 512 + sge;
  tpA[2] = a2 + (size_t)(bm + srow) * 512 + sge;

  const int bcol = lane >> 2;
  const int bge  = (lane & 3) * 8;

  int aoff[4];
#pragma unroll
  for (int i = 0; i < 4; ++i)
    aoff[i] = (wm * 64 + i * 16 + l15) * 32 + kge;
  const int boff = (wn * 16 + l15) * 32 + kge;

  f32x4 acc[3][4] = {};   // [gate][mi]

  for (int s = 0; s < 16; ++s) {
    const int k0 = s * 32;
#pragma unroll
    for (int p = 0; p < 3; ++p) {
      gl_lds16(tpA[p] + k0,                    &As[p][w * 512]);
      gl_lds16(tpA[p] + (size_t)64 * 512 + k0, &As[p][2048 + w * 512]);
    }
    for (int qq = w; qq < 9; qq += 4) {
      const int gg = qq / 3, pp = qq - gg * 3;
      const __bf16* wp = (pp == 0) ? wb0 : (pp == 1) ? wb1 : wb2;
      const __bf16* src =
          wp + (size_t)(gg * 512 + bn + bcol) * 512 + bge + k0;
      gl_lds16(src,                     &Bs[qq][0]);
      gl_lds16(src + (size_t)16 * 512,  &Bs[qq][512]);
    }
    __syncthreads();

    bf16x8 Af[3][4];
#pragma unroll
    for (int mi = 0; mi < 4; ++mi) {
      Af[0][mi] = *(const bf16x8*)&As[0][aoff[mi]];
      Af[1][mi] = *(const bf16x8*)&As[1][aoff[mi]];
      Af[2][mi] = *(const bf16x8*)&As[2][aoff[mi]];
    }
#pragma unroll
    for (int gg = 0; gg < 3; ++gg) {
      bf16x8 B0 = *(const bf16x8*)&Bs[gg * 3 + 0][boff];
      bf16x8 B1 = *(const bf16x8*)&Bs[gg * 3 + 1][boff];
      bf16x8 B2 = *(const bf16x8*)&Bs[gg * 3 + 2][boff];
#pragma unroll
      for (int mi = 0; mi < 4; ++mi) {
        f32x4 c = acc[gg][mi];
        MFMA9(c, Af[0][mi], Af[1][mi], Af[2][mi], B0, B1, B2);
        acc[gg][mi] = c;
      }
    }
    __syncthreads();
  }

  const int col = bn + wn * 16 + l15;
  const float bvr = bias[col];
  const float bvz = bias[512 + col];
  const float bvn = bias[1024 + col];
#pragma unroll
  for (int mi = 0; mi < 4; ++mi) {
    const int row0 = bm + wm * 64 + mi * 16 + (lane >> 4) * 4;
#pragma unroll
    for (int rr = 0; rr < 4; ++rr) {
      const int row = row0 + rr;
      const int tok = curTok[row];
      const float* e = Eih0 + (size_t)tok * 1536;
      const size_t idx = (size_t)row * 512 + col;
      float hold = __fadd_rn(__fadd_rn((float)a0[idx], (float)a1[idx]),
                             (float)a2[idx]);
      float hnew = gru_h(e[col], e[512 + col], e[1024 + col],
                         acc[0][mi][rr] + bvr, acc[1][mi][rr] + bvz,
                         acc[2][mi][rr] + bvn, hold);
      __bf16 s0, s1, s2;
      split3(hnew, s0, s1, s2);
      q0[idx] = s0; q1[idx] = s1; q2[idx] = s2;
    }
  }
}

// ---------------- splitters / transpose / gates(layer1) ---------------------
__global__ __launch_bounds__(256) void k_split(
    const float* __restrict__ in, __bf16* __restrict__ p0,
    __bf16* __restrict__ p1, __bf16* __restrict__ p2, int total) {
  int i = blockIdx.x * 256 + threadIdx.x;
  if (i >= total) return;
  __bf16 a0, a1, a2;
  split3(in[i], a0, a1, a2);
  p0[i] = a0; p1[i] = a1; p2[i] = a2;
}

__global__ __launch_bounds__(256) void k_transpose(
    const float* __restrict__ in, float* __restrict__ out, int R, int C) {
  __shared__ float tile[32][33];
  int c0 = blockIdx.x * 32, r0 = blockIdx.y * 32;
  int x = threadIdx.x, y0 = threadIdx.y;
  for (int i = y0; i < 32; i += 8) {
    int r = r0 + i, c = c0 + x;
    tile[i][x] = (r < R && c < C) ? in[(size_t)r * C + c] : 0.0f;
  }
  __syncthreads();
  for (int i = y0; i < 32; i += 8) {
    int orow = c0 + i, oc = r0 + x;
    if (orow < C && oc < R) out[(size_t)orow * R + oc] = tile[x][i];
  }
}

__global__ __launch_bounds__(256) void k_gates(
    const float* __restrict__ gi_mat, const int* __restrict__ gi_rows,
    const float* __restrict__ gh,
    __bf16* __restrict__ p0, __bf16* __restrict__ p1, __bf16* __restrict__ p2) {
  int idx = blockIdx.x * 256 + threadIdx.x;
  int b = idx >> 9, j = idx & 511;
  int gr = gi_rows ? gi_rows[b] : b;
  const float* gi = gi_mat + (size_t)gr * 1536;
  const float* gp = gh + (size_t)b * 1536;
  float ir = gi[j], iz = gi[512 + j], in_ = gi[1024 + j];
  float hr = gp[j], hz = gp[512 + j], hn = gp[1024 + j];
  float r = xla_sigmoid(__fadd_rn(ir, hr));
  float u = xla_sigmoid(__fadd_rn(iz, hz));
  float n = xla_tanh(__fadd_rn(in_, __fmul_rn(r, hn)));
  float hold = __fadd_rn(__fadd_rn((float)p0[idx], (float)p1[idx]), (float)p2[idx]);
  float t1 = __fmul_rn(__fsub_rn(1.0f, u), n);
  float t2 = __fmul_rn(u, hold);
  float hnew = __fadd_rn(t1, t2);
  __bf16 a0, a1, a2;
  split3(hnew, a0, a1, a2);
  p0[idx] = a0; p1[idx] = a1; p2[idx] = a2;
}

// ---------------- sampling (4-pass byte-radix select; same threshold) -------
__global__ __launch_bounds__(256) void k_sample(
    const float* __restrict__ logits, int* __restrict__ cur,
    int* __restrict__ finished, int* __restrict__ outTok,
    int t, uint32_t sk0, uint32_t sk1) {
  const int row = blockIdx.x;
  const int tid = threadIdx.x;
  __shared__ float sl[kVoc];
  __shared__ uint32_t skeys[kVoc];
  __shared__ int  cnt[256];
  __shared__ int  sfx[257];
  __shared__ int  wtot[4];
  __shared__ uint32_t sPrefix;
  __shared__ int  sNeed;
  __shared__ float redf[4];
  __shared__ int   redix[4];

  const float* lp = logits + (size_t)row * kVoc;
  for (int c = tid; c < kVoc; c += 256) {
    float v = lp[c];
    if (c == kBos || c == kPad) v = kNeg;
    if (c == kEos && t < 1 + kEffMin) v = kNeg;
    sl[c] = v;
    uint32_t u = __float_as_uint(v);
    skeys[c] = u ^ ((u >> 31) ? 0xFFFFFFFFu : 0x80000000u);
  }
  __syncthreads();

  // radix-select: T = 40th largest key == max T with count(key>=T) >= 40
  uint32_t prefix = 0u;
  int need = kTopK;
  const int lane = tid & 63, wv = tid >> 6;
  for (int by = 3; by >= 0; --by) {
    cnt[tid] = 0;
    __syncthreads();
    const int sh = by * 8;
    const uint32_t hiMask = (by == 3) ? 0u : (0xFFFFFFFFu << (sh + 8));
    for (int c = tid; c < kVoc; c += 256) {
      uint32_t k = skeys[c];
      if ((k & hiMask) == prefix) atomicAdd(&cnt[(k >> sh) & 255], 1);
    }
    __syncthreads();
    // suffix sums over 256 buckets: wave wv covers buckets [wv*64, wv*64+64)
    int val = cnt[tid];
#pragma unroll
    for (int off = 1; off < 64; off <<= 1) {
      int other = __shfl_down(val, off, 64);
      if (lane + off < 64) val += other;
    }
    int wt = __shfl(val, 0, 64);
    if (lane == 0) wtot[wv] = wt;
    __syncthreads();
    int tail = 0;
    for (int u = wv + 1; u < 4; ++u) tail += wtot[u];
    sfx[tid] = val + tail;
    if (tid == 0) sfx[256] = 0;
    __syncthreads();
    // unique digit d: sfx[d] >= need && sfx[d+1] < need
    if (sfx[tid] >= need && sfx[tid + 1] < need) {
      sPrefix = prefix | ((uint32_t)tid << sh);
      sNeed = need - sfx[tid + 1];
    }
    __syncthreads();
    prefix = sPrefix;
    need = sNeed;
    __syncthreads();
  }

  // gumbel + argmax over kept entries (key >= prefix), unchanged
  float best = -3.4e38f; int bidx = kVoc;
  for (int c = tid; c < kVoc; c += 256) {
    if (skeys[c] >= prefix) {
      uint32_t idx = (uint32_t)row * (uint32_t)kVoc + (uint32_t)c;
      uint32_t w1, w2, bits;
#if PARTITIONABLE
      tf2x32(sk0, sk1, 0u, idx, w1, w2);
      bits = w1 ^ w2;
#else
      const uint32_t HH = (uint32_t)((uint64_t)kBatch * kVoc / 2);
      if (idx < HH) { tf2x32(sk0, sk1, idx, idx + HH, w1, w2); bits = w1; }
      else          { tf2x32(sk0, sk1, idx - HH, idx, w1, w2); bits = w2; }
#endif
      uint32_t fb = (bits >> 9) | 0x3f800000u;
      float uf = __fsub_rn(__uint_as_float(fb), 1.0f);
      if (uf == 0.0f) uf = kTiny;
      float g = -logf(-logf(uf));
      float tot = __fadd_rn(g, sl[c]);
      if (tot > best || (tot == best && c < bidx)) { best = tot; bidx = c; }
    }
  }
#pragma unroll
  for (int off = 32; off; off >>= 1) {
    float ov = __shfl_down(best, off, 64);
    int   oi = __shfl_down(bidx, off, 64);
    if (ov > best || (ov == best && oi < bidx)) { best = ov; bidx = oi; }
  }
  if ((tid & 63) == 0) { redf[tid >> 6] = best; redix[tid >> 6] = bidx; }
  __syncthreads();
  if (tid == 0) {
    for (int w = 1; w < 4; ++w) {
      if (redf[w] > best || (redf[w] == best && redix[w] < bidx)) {
        best = redf[w]; bidx = redix[w];
      }
    }
    int fin = finished[row];
    int nxt = fin ? kPad : bidx;
    outTok[(size_t)row * kMaxLen + t] = nxt;
    cur[row] = nxt;
    finished[row] = fin | (nxt == kEos);
  }
}

__global__ __launch_bounds__(256) void k_init(int* cur, int* finished, int* outTok) {
  int i = blockIdx.x * 256 + threadIdx.x;
  if (i < kBatch) {
    cur[i] = kBos;
    finished[i] = 0;
    outTok[(size_t)i * kMaxLen] = kBos;
  }
}

extern "C" void kernel_launch(void* const* d_in, const int* in_sizes, int n_in,
                              void* d_out, int out_size, void* d_ws, size_t ws_size,
                              hipStream_t stream) {
  (void)in_sizes; (void)n_in; (void)out_size; (void)ws_size;
  const float* z      = (const float*)d_in[0];
  const float* embed  = (const float*)d_in[1];
  const float* w_lh   = (const float*)d_in[2];
  const float* b_lh   = (const float*)d_in[3];
  const float* w_ih0  = (const float*)d_in[4];
  const float* w_hh0  = (const float*)d_in[5];
  const float* b_ih0  = (const float*)d_in[6];
  const float* b_hh0  = (const float*)d_in[7];
  const float* w_ih1  = (const float*)d_in[8];
  const float* w_hh1  = (const float*)d_in[9];
  const float* b_ih1  = (const float*)d_in[10];
  const float* b_hh1  = (const float*)d_in[11];
  const float* w_out  = (const float*)d_in[12];
  const float* b_out  = (const float*)d_in[13];
  int* out = (int*)d_out;

  // ---- workspace: round-9 layout (121.2 MB proven) ----
  char* base = (char*)d_ws;
  int* curTok   = (int*)base;
  int* finished = curTok + kBatch;
  __bf16* q = (__bf16*)(base + 32768);
  __bf16* whh0[3]; __bf16* wih1[3]; __bf16* whh1[3]; __bf16* wout[3];
  for (int i = 0; i < 3; ++i) { whh0[i] = q; q += (size_t)1536 * 512; }
  for (int i = 0; i < 3; ++i) { wih1[i] = q; q += (size_t)1536 * 512; }
  for (int i = 0; i < 3; ++i) { whh1[i] = q; q += (size_t)1536 * 512; }
  for (int i = 0; i < 3; ++i) { wout[i] = q; q += (size_t)2048 * 512; }
  __bf16* hs0A[3]; __bf16* hs1[3];
  for (int i = 0; i < 3; ++i) { hs0A[i] = q; q += (size_t)kBatch * kHid; }
  for (int i = 0; i < 3; ++i) { hs1[i] = q; q += (size_t)kBatch * kHid; }
  float* f = (float*)q;
  float* Eih0 = f; f += (size_t)kVoc * 1536;
  float* ghA  = f; f += (size_t)kBatch * 1536;
  float* gi1  = f; f += (size_t)kBatch * 1536;
  float* logits = ghA;                       // spans ghA+gi1 (both dead then)
  float* wt_ih0 = ghA;                       // init-only aliases
  float* wt_lh  = ghA + (size_t)128 * 1536;
  float* h0tmp  = gi1;
  float* h1tmp  = gi1 + (size_t)kBatch * kHid;
  __bf16* hs0B[3];
  { __bf16* hb = (__bf16*)f;
    for (int i = 0; i < 3; ++i) { hs0B[i] = hb; hb += (size_t)kBatch * kHid; } }

  dim3 blk(256);
  dim3 tblk(32, 8);

  // ---- one-time setup ----
  k_transpose<<<dim3(4, 48), tblk, 0, stream>>>(w_ih0, wt_ih0, 1536, 128);
  k_transpose<<<dim3(4, 32), tblk, 0, stream>>>(w_lh,  wt_lh,  1024, 128);
  k_split<<<dim3(1536 * 512 / 256), blk, 0, stream>>>(w_hh0, whh0[0], whh0[1], whh0[2], 1536 * 512);
  k_split<<<dim3(1536 * 512 / 256), blk, 0, stream>>>(w_ih1, wih1[0], wih1[1], wih1[2], 1536 * 512);
  k_split<<<dim3(1536 * 512 / 256), blk, 0, stream>>>(w_hh1, whh1[0], whh1[1], whh1[2], 1536 * 512);
  k_split<<<dim3(2048 * 512 / 256), blk, 0, stream>>>(w_out, wout[0], wout[1], wout[2], 2048 * 512);

  gemm2<0><<<dim3(12, 16, 1), blk, 0, stream>>>(
      embed, wt_ih0, b_ih0, Eih0, embed, wt_ih0, b_ih0, Eih0,
      kEmb, 1536, 1536, kEmb);
  gemm2<1><<<dim3(4, 32, 2), blk, 0, stream>>>(
      z, wt_lh,       b_lh,       h0tmp,
      z, wt_lh + 512, b_lh + 512, h1tmp,
      kEmb, 1024, kHid, kEmb);
  k_split<<<dim3(kBatch * kHid / 256), blk, 0, stream>>>(h0tmp, hs0A[0], hs0A[1], hs0A[2], kBatch * kHid);
  k_split<<<dim3(kBatch * kHid / 256), blk, 0, stream>>>(h1tmp, hs1[0], hs1[1], hs1[2], kBatch * kHid);
  k_init<<<dim3((kBatch + 255) / 256), blk, 0, stream>>>(curTok, finished, out);

  uint32_t key0 = 0u, key1 = 1u;   // jax.random.key(1)
  for (int t = 1; t < kMaxLen; ++t) {
    uint32_t nk0, nk1, s0, s1;
#if PARTITIONABLE
    tf2x32(key0, key1, 0u, 0u, nk0, nk1);
    tf2x32(key0, key1, 0u, 1u, s0, s1);
#else
    uint32_t a0, b0w, a1, b1w;
    tf2x32(key0, key1, 0u, 2u, a0, b0w);
    tf2x32(key0, key1, 1u, 3u, a1, b1w);
    nk0 = a0; nk1 = a1; s0 = b0w; s1 = b1w;
#endif
    __bf16** h0in  = (t & 1) ? hs0A : hs0B;
    __bf16** h0out = (t & 1) ? hs0B : hs0A;

    // layer 0: fused gh0-GEMM + gates (ping-pong h0 planes)
    gemm_gru0<<<dim3(16, 32), blk, 0, stream>>>(
        h0in[0], h0in[1], h0in[2], whh0[0], whh0[1], whh0[2],
        b_hh0, Eih0, curTok, h0out[0], h0out[1], h0out[2]);

    // layer 1: dual GEMM (gi1, gh1) then gates (round-9 proven structure)
    GemmArgs gia{h0out[0], h0out[1], h0out[2], wih1[0], wih1[1], wih1[2], b_ih1, gi1};
    GemmArgs gha{hs1[0], hs1[1], hs1[2], whh1[0], whh1[1], whh1[2], b_hh1, ghA};
    gemm_mx3<<<dim3(12, 32, 2), blk, 0, stream>>>(gia, gha, 1536);
    k_gates<<<dim3(kBatch * kHid / 256), blk, 0, stream>>>(
        gi1, nullptr, ghA, hs1[0], hs1[1], hs1[2]);

    // logits + sample
    GemmArgs gla{hs1[0], hs1[1], hs1[2], wout[0], wout[1], wout[2], b_out, logits};
    gemm_mx3<<<dim3(16, 32, 1), blk, 0, stream>>>(gla, gla, 2048);
    k_sample<<<dim3(kBatch), blk, 0, stream>>>(logits, curTok, finished, out, t, s0, s1);

    key0 = nk0; key1 = nk1;
  }
}

// Round 13
// 15885.179 us; speedup vs baseline: 1.2469x; 1.0261x over previous
//
#include <hip/hip_runtime.h>
#include <cstdint>
#include <cstddef>

#ifndef PARTITIONABLE
#define PARTITIONABLE 1
#endif

namespace {
constexpr int kBatch  = 4096;
constexpr int kEmb    = 128;
constexpr int kHid    = 512;
constexpr int kVoc    = 2048;
constexpr int kMaxLen = 64;
constexpr int kTopK   = 40;
constexpr int kBos = 1, kEos = 2, kPad = 0;
constexpr int kEffMin = 20;
constexpr float kNeg  = -1.0e9f;
constexpr float kTiny = 1.17549435082228751e-38f;
}

typedef __bf16 bf16x8 __attribute__((ext_vector_type(8)));
typedef float  f32x4  __attribute__((ext_vector_type(4)));

__host__ __device__ inline void tf2x32(uint32_t k0, uint32_t k1,
                                       uint32_t x0, uint32_t x1,
                                       uint32_t& o0, uint32_t& o1) {
  uint32_t ks0 = k0, ks1 = k1, ks2 = k0 ^ k1 ^ 0x1BD11BDAu;
  x0 += ks0; x1 += ks1;
#define TFR(r) { x0 += x1; x1 = (x1 << (r)) | (x1 >> (32 - (r))); x1 ^= x0; }
  TFR(13) TFR(15) TFR(26) TFR(6)   x0 += ks1; x1 += ks2 + 1u;
  TFR(17) TFR(29) TFR(16) TFR(24)  x0 += ks2; x1 += ks0 + 2u;
  TFR(13) TFR(15) TFR(26) TFR(6)   x0 += ks0; x1 += ks1 + 3u;
  TFR(17) TFR(29) TFR(16) TFR(24)  x0 += ks1; x1 += ks2 + 4u;
  TFR(13) TFR(15) TFR(26) TFR(6)   x0 += ks2; x1 += ks0 + 5u;
#undef TFR
  o0 = x0; o1 = x1;
}

__device__ __forceinline__ float xla_tanh(float x) {
  float ax = fabsf(x);
  float xc = fminf(fmaxf(x, -9.0f), 9.0f);
  float x2 = __fmul_rn(xc, xc);
  float num = -2.76076847742355e-16f;
  num = __fadd_rn(__fmul_rn(x2, num), 2.00018790482477e-13f);
  num = __fadd_rn(__fmul_rn(x2, num), -8.60467152213735e-11f);
  num = __fadd_rn(__fmul_rn(x2, num), 5.12229709037114e-08f);
  num = __fadd_rn(__fmul_rn(x2, num), 1.48572235717979e-05f);
  num = __fadd_rn(__fmul_rn(x2, num), 6.37261928875436e-04f);
  num = __fadd_rn(__fmul_rn(x2, num), 4.89352455891786e-03f);
  num = __fmul_rn(xc, num);
  float den = 1.19825839466702e-06f;
  den = __fadd_rn(__fmul_rn(x2, den), 1.18534705686654e-04f);
  den = __fadd_rn(__fmul_rn(x2, den), 2.26843463243900e-03f);
  den = __fadd_rn(__fmul_rn(x2, den), 4.89352518554385e-03f);
  return (ax < 4.0e-04f) ? x : __fdiv_rn(num, den);
}

__device__ __forceinline__ float xla_sigmoid(float x) {
  return __fdiv_rn(1.0f, __fadd_rn(1.0f, expf(-x)));
}

__device__ __forceinline__ void gl_lds16(const void* g, void* l) {
  __builtin_amdgcn_global_load_lds(
      (const __attribute__((address_space(1))) void*)g,
      (__attribute__((address_space(3))) void*)l, 16, 0, 0);
}

__device__ __forceinline__ void split3(float a, __bf16& a0, __bf16& a1, __bf16& a2) {
  a0 = (__bf16)a;
  float r1 = __fsub_rn(a, (float)a0);
  a1 = (__bf16)r1;
  float r2 = __fsub_rn(r1, (float)a1);
  a2 = (__bf16)r2;   // exact: 3x8 mantissa bits cover f32's 24
}

__device__ __forceinline__ float gru_h(float gir, float giz, float gin,
                                       float ghr, float ghz, float ghn,
                                       float hold) {
  float r = xla_sigmoid(__fadd_rn(gir, ghr));
  float u = xla_sigmoid(__fadd_rn(giz, ghz));
  float n = xla_tanh(__fadd_rn(gin, __fmul_rn(r, ghn)));
  float t1 = __fmul_rn(__fsub_rn(1.0f, u), n);
  float t2 = __fmul_rn(u, hold);
  return __fadd_rn(t1, t2);
}

#define MFMA9(c, A0_, A1_, A2_, B0_, B1_, B2_) do {                          \
    c = __builtin_amdgcn_mfma_f32_16x16x32_bf16(A2_, B2_, c, 0, 0, 0);       \
    c = __builtin_amdgcn_mfma_f32_16x16x32_bf16(A2_, B1_, c, 0, 0, 0);       \
    c = __builtin_amdgcn_mfma_f32_16x16x32_bf16(A1_, B2_, c, 0, 0, 0);       \
    c = __builtin_amdgcn_mfma_f32_16x16x32_bf16(A2_, B0_, c, 0, 0, 0);       \
    c = __builtin_amdgcn_mfma_f32_16x16x32_bf16(A1_, B1_, c, 0, 0, 0);       \
    c = __builtin_amdgcn_mfma_f32_16x16x32_bf16(A0_, B2_, c, 0, 0, 0);       \
    c = __builtin_amdgcn_mfma_f32_16x16x32_bf16(A1_, B0_, c, 0, 0, 0);       \
    c = __builtin_amdgcn_mfma_f32_16x16x32_bf16(A0_, B1_, c, 0, 0, 0);       \
    c = __builtin_amdgcn_mfma_f32_16x16x32_bf16(A0_, B0_, c, 0, 0, 0);       \
  } while (0)

// ---------------- f32 vector GEMM (init only; proven rounds 1-2) ------------
template <int ACT>
__global__ __launch_bounds__(256) void gemm2(
    const float* __restrict__ A0, const float* __restrict__ B0,
    const float* __restrict__ bias0, float* __restrict__ C0,
    const float* __restrict__ A1, const float* __restrict__ B1,
    const float* __restrict__ bias1, float* __restrict__ C1,
    int lda, int ldb, int ldc, int K) {
  __shared__ __attribute__((aligned(16))) float As[2][128 * 16];
  __shared__ __attribute__((aligned(16))) float Bs[2][16 * 128];

  const float* A    = blockIdx.z ? A1 : A0;
  const float* Bt   = blockIdx.z ? B1 : B0;
  const float* bias = blockIdx.z ? bias1 : bias0;
  float*       C    = blockIdx.z ? C1 : C0;

  const int tid = threadIdx.x;
  const int w = tid >> 6, l = tid & 63;
  const int bm = blockIdx.y * 128;
  const int bn = blockIdx.x * 128;
  const int tx = tid & 15, ty = tid >> 4;
  const int t3 = ty & 3;

  const int arow  = w * 16 + (l >> 2);
  const int agran = (l & 3) ^ ((l >> 2) & 3);
  const float* pA = A + (size_t)(bm + arow) * lda + agran * 4;
  const int bk = w * 2 + (l >> 5);
  const int bnc = (l & 31) * 4;
  const float* pB = Bt + (size_t)bk * ldb + bn + bnc;

  float acc[8][8];
#pragma unroll
  for (int i = 0; i < 8; ++i)
#pragma unroll
    for (int j = 0; j < 8; ++j) acc[i][j] = 0.0f;

  const int nt = K >> 4;
  gl_lds16(pA,            &As[0][w * 256]);
  gl_lds16(pA + 64 * lda, &As[0][(4 + w) * 256]);
  gl_lds16(pB,            &Bs[0][w * 256]);
  gl_lds16(pB + (size_t)8 * ldb, &Bs[0][(4 + w) * 256]);
  __syncthreads();

  for (int t = 0; t < nt; ++t) {
    const int cur = t & 1;
    if (t + 1 < nt) {
      const float* qA = pA + (t + 1) * 16;
      const float* qB = pB + (size_t)(t + 1) * 16 * ldb;
      gl_lds16(qA,            &As[cur ^ 1][w * 256]);
      gl_lds16(qA + 64 * lda, &As[cur ^ 1][(4 + w) * 256]);
      gl_lds16(qB,            &Bs[cur ^ 1][w * 256]);
      gl_lds16(qB + (size_t)8 * ldb, &Bs[cur ^ 1][(4 + w) * 256]);
    }
    const float* as = As[cur];
    const float* bs = Bs[cur];
#pragma unroll
    for (int g = 0; g < 4; ++g) {
      float4 bv0[4], bv1[4];
#pragma unroll
      for (int q = 0; q < 4; ++q) {
        bv0[q] = *(const float4*)&bs[(g * 4 + q) * 128 + tx * 4];
        bv1[q] = *(const float4*)&bs[(g * 4 + q) * 128 + 64 + tx * 4];
      }
#pragma unroll
      for (int ii = 0; ii < 8; ++ii) {
        float4 a = *(const float4*)&as[(ty + 16 * ii) * 16 + ((g ^ t3) * 4)];
        float ak[4] = {a.x, a.y, a.z, a.w};
#pragma unroll
        for (int q = 0; q < 4; ++q) {
          const float av_ = ak[q];
          const float4 b0 = bv0[q], b1 = bv1[q];
          acc[ii][0] += av_ * b0.x; acc[ii][1] += av_ * b0.y;
          acc[ii][2] += av_ * b0.z; acc[ii][3] += av_ * b0.w;
          acc[ii][4] += av_ * b1.x; acc[ii][5] += av_ * b1.y;
          acc[ii][6] += av_ * b1.z; acc[ii][7] += av_ * b1.w;
        }
      }
    }
    __syncthreads();
  }

  const int c0 = bn + tx * 4, c1 = bn + 64 + tx * 4;
  const float4 bs0 = *(const float4*)&bias[c0];
  const float4 bs1 = *(const float4*)&bias[c1];
#pragma unroll
  for (int ii = 0; ii < 8; ++ii) {
    const int r = bm + ty + 16 * ii;
    float4 o0, o1;
    o0.x = acc[ii][0] + bs0.x; o0.y = acc[ii][1] + bs0.y;
    o0.z = acc[ii][2] + bs0.z; o0.w = acc[ii][3] + bs0.w;
    o1.x = acc[ii][4] + bs1.x; o1.y = acc[ii][5] + bs1.y;
    o1.z = acc[ii][6] + bs1.z; o1.w = acc[ii][7] + bs1.w;
    if (ACT == 1) {
      o0.x = xla_tanh(o0.x); o0.y = xla_tanh(o0.y);
      o0.z = xla_tanh(o0.z); o0.w = xla_tanh(o0.w);
      o1.x = xla_tanh(o1.x); o1.y = xla_tanh(o1.y);
      o1.z = xla_tanh(o1.z); o1.w = xla_tanh(o1.w);
    }
    *(float4*)(C + (size_t)r * ldc + c0) = o0;
    *(float4*)(C + (size_t)r * ldc + c1) = o1;
  }
}

// ---------------- bf16x3 MFMA GEMM (round-6 proven body + XCD swizzle) ------
struct GemmArgs {
  const __bf16 *a0, *a1, *a2;
  const __bf16 *b0, *b1, *b2;
  const float* bias;
  float* c;
};

__global__ __launch_bounds__(256, 3) void gemm_mx3(
    GemmArgs g0, GemmArgs g1, int N) {
  __shared__ __attribute__((aligned(16))) __bf16 lds[6 * 4096];  // 48 KiB

  const GemmArgs g = blockIdx.z ? g1 : g0;
  const int tid = threadIdx.x;
  const int nwg = gridDim.x * gridDim.y;
  const int lin = blockIdx.y * gridDim.x + blockIdx.x;
  const int swz = (lin & 7) * (nwg >> 3) + (lin >> 3);
  const int bm = (swz / gridDim.x) * 128;
  const int bn = (swz % gridDim.x) * 128;
  const int lane = tid & 63;
  const int w  = tid >> 6;
  const int wm = w & 1;
  const int wn = w >> 1;
  const int l15 = lane & 15;
  const int kge = (lane >> 4) * 8;

  const int srow = tid >> 2;
  const int sge  = (tid & 3) * 8;
  const __bf16* tp[6];
  tp[0] = g.a0 + (size_t)(bm + srow) * 512 + sge;
  tp[1] = g.a1 + (size_t)(bm + srow) * 512 + sge;
  tp[2] = g.a2 + (size_t)(bm + srow) * 512 + sge;
  tp[3] = g.b0 + (size_t)(bn + srow) * 512 + sge;
  tp[4] = g.b1 + (size_t)(bn + srow) * 512 + sge;
  tp[5] = g.b2 + (size_t)(bn + srow) * 512 + sge;

  int aoff[4], boff[4];
#pragma unroll
  for (int i = 0; i < 4; ++i) {
    aoff[i] = (wm * 64 + i * 16 + l15) * 32 + kge;
    boff[i] = (wn * 64 + i * 16 + l15) * 32 + kge;
  }

  f32x4 acc[4][4] = {};

  for (int s = 0; s < 16; ++s) {
    const int k0 = s * 32;
#pragma unroll
    for (int p = 0; p < 6; ++p) {
      gl_lds16(tp[p] + k0,                    &lds[p * 4096 + w * 512]);
      gl_lds16(tp[p] + (size_t)64 * 512 + k0, &lds[p * 4096 + 2048 + w * 512]);
    }
    __syncthreads();

    bf16x8 Af[3][4];
#pragma unroll
    for (int mi = 0; mi < 4; ++mi) {
      Af[0][mi] = *(const bf16x8*)&lds[0 * 4096 + aoff[mi]];
      Af[1][mi] = *(const bf16x8*)&lds[1 * 4096 + aoff[mi]];
      Af[2][mi] = *(const bf16x8*)&lds[2 * 4096 + aoff[mi]];
    }
#pragma unroll
    for (int nj = 0; nj < 4; ++nj) {
      bf16x8 B0 = *(const bf16x8*)&lds[3 * 4096 + boff[nj]];
      bf16x8 B1 = *(const bf16x8*)&lds[4 * 4096 + boff[nj]];
      bf16x8 B2 = *(const bf16x8*)&lds[5 * 4096 + boff[nj]];
#pragma unroll
      for (int mi = 0; mi < 4; ++mi) {
        f32x4 c = acc[mi][nj];
        MFMA9(c, Af[0][mi], Af[1][mi], Af[2][mi], B0, B1, B2);
        acc[mi][nj] = c;
      }
    }
    __syncthreads();
  }

#pragma unroll
  for (int mi = 0; mi < 4; ++mi) {
    const int row0 = bm + wm * 64 + mi * 16 + (lane >> 4) * 4;
#pragma unroll
    for (int nj = 0; nj < 4; ++nj) {
      const int col = bn + wn * 64 + nj * 16 + l15;
      const float bv = g.bias[col];
      f32x4 v = acc[mi][nj];
#pragma unroll
      for (int r = 0; r < 4; ++r)
        g.c[(size_t)(row0 + r) * N + col] = v[r] + bv;
    }
  }
}

// ---------------- fused gh0-GEMM + gates0 (layer 0; proven round 9) ---------
__global__ __launch_bounds__(256, 2) void gemm_gru0(
    const __bf16* __restrict__ a0, const __bf16* __restrict__ a1,
    const __bf16* __restrict__ a2,
    const __bf16* __restrict__ wb0, const __bf16* __restrict__ wb1,
    const __bf16* __restrict__ wb2,
    const float* __restrict__ bias, const float* __restrict__ Eih0,
    const int* __restrict__ curTok,
    __bf16* __restrict__ q0, __bf16* __restrict__ q1,
    __bf16* __restrict__ q2) {
  __shared__ __attribute__((aligned(16))) __bf16 As[3][4096];  // 24 KiB
  __shared__ __attribute__((aligned(16))) __bf16 Bs[9][1024];  // 18 KiB

  const int tid = threadIdx.x;
  const int nwg = gridDim.x * gridDim.y;         // 512
  const int lin = blockIdx.y * gridDim.x + blockIdx.x;
  const int swz = (lin & 7) * (nwg >> 3) + (lin >> 3);
  const int bm = (swz / gridDim.x) * 128;
  const int bn = (swz % gridDim.x) * 32;
  const int lane = tid & 63;
  const int w  = tid >> 6;
  const int wm = w & 1;
  const int wn = w >> 1;
  const int l15 = lane & 15;
  const int kge = (lane >> 4) * 8;

  const int srow = tid >> 2;
  const int sge  = (tid & 3) * 8;
  const __bf16* tpA[3];
  tpA[0] = a0 + (size_t)(bm + srow) * 512 + sge;
  tpA[1] = a1 + (size_t)(bm + srow) * 512 + sge;
  tpA[2] = a2 + (size_t)(bm + srow) * 512 + sge;

  const int bcol = lane >> 2;
  const int bge  = (lane & 3) * 8;

  int aoff[4];
#pragma unroll
  for (int i = 0; i < 4; ++i)
    aoff[i] = (wm * 64 + i * 16 + l15) * 32 + kge;
  const int boff = (wn * 16 + l15) * 32 + kge;

  f32x4 acc[3][4] = {};   // [gate][mi]

  for (int s = 0; s < 16; ++s) {
    const int k0 = s * 32;
#pragma unroll
    for (int p = 0; p < 3; ++p) {
      gl_lds16(tpA[p] + k0,                    &As[p][w * 512]);
      gl_lds16(tpA[p] + (size_t)64 * 512 + k0, &As[p][2048 + w * 512]);
    }
    for (int qq = w; qq < 9; qq += 4) {
      const int gg = qq / 3, pp = qq - gg * 3;
      const __bf16* wp = (pp == 0) ? wb0 : (pp == 1) ? wb1 : wb2;
      const __bf16* src =
          wp + (size_t)(gg * 512 + bn + bcol) * 512 + bge + k0;
      gl_lds16(src,                     &Bs[qq][0]);
      gl_lds16(src + (size_t)16 * 512,  &Bs[qq][512]);
    }
    __syncthreads();

    bf16x8 Af[3][4];
#pragma unroll
    for (int mi = 0; mi < 4; ++mi) {
      Af[0][mi] = *(const bf16x8*)&As[0][aoff[mi]];
      Af[1][mi] = *(const bf16x8*)&As[1][aoff[mi]];
      Af[2][mi] = *(const bf16x8*)&As[2][aoff[mi]];
    }
#pragma unroll
    for (int gg = 0; gg < 3; ++gg) {
      bf16x8 B0 = *(const bf16x8*)&Bs[gg * 3 + 0][boff];
      bf16x8 B1 = *(const bf16x8*)&Bs[gg * 3 + 1][boff];
      bf16x8 B2 = *(const bf16x8*)&Bs[gg * 3 + 2][boff];
#pragma unroll
      for (int mi = 0; mi < 4; ++mi) {
        f32x4 c = acc[gg][mi];
        MFMA9(c, Af[0][mi], Af[1][mi], Af[2][mi], B0, B1, B2);
        acc[gg][mi] = c;
      }
    }
    __syncthreads();
  }

  const int col = bn + wn * 16 + l15;
  const float bvr = bias[col];
  const float bvz = bias[512 + col];
  const float bvn = bias[1024 + col];
#pragma unroll
  for (int mi = 0; mi < 4; ++mi) {
    const int row0 = bm + wm * 64 + mi * 16 + (lane >> 4) * 4;
#pragma unroll
    for (int rr = 0; rr < 4; ++rr) {
      const int row = row0 + rr;
      const int tok = curTok[row];
      const float* e = Eih0 + (size_t)tok * 1536;
      const size_t idx = (size_t)row * 512 + col;
      float hold = __fadd_rn(__fadd_rn((float)a0[idx], (float)a1[idx]),
                             (float)a2[idx]);
      float hnew = gru_h(e[col], e[512 + col], e[1024 + col],
                         acc[0][mi][rr] + bvr, acc[1][mi][rr] + bvz,
                         acc[2][mi][rr] + bvn, hold);
      __bf16 s0, s1, s2;
      split3(hnew, s0, s1, s2);
      q0[idx] = s0; q1[idx] = s1; q2[idx] = s2;
    }
  }
}

// ---------------- fused layer-1 (BM=128, phase-split, PING-PONG h1) ---------
// Two sub-phases per K-slab reuse the same 42 KiB LDS: {x-planes + w_ih1
// subtiles -> MFMA gi} then {h1-planes + w_hh1 subtiles -> MFMA gh}.
// Weight economics = R9 dual (32 row-blocks). Per-accumulator MFMA order and
// gate math bit-identical to the dual+k_gates path. h1 ping-pong (R11 fix).
__global__ __launch_bounds__(256, 2) void gemm_gru1(
    const __bf16* __restrict__ x0, const __bf16* __restrict__ x1,
    const __bf16* __restrict__ x2,        // h0' planes (gi A operand)
    const __bf16* __restrict__ wi0, const __bf16* __restrict__ wi1,
    const __bf16* __restrict__ wi2,
    const __bf16* __restrict__ wh0, const __bf16* __restrict__ wh1,
    const __bf16* __restrict__ wh2,
    const float* __restrict__ bias_i, const float* __restrict__ bias_h,
    const __bf16* __restrict__ hi0, const __bf16* __restrict__ hi1,
    const __bf16* __restrict__ hi2,       // h1 IN planes
    __bf16* __restrict__ ho0, __bf16* __restrict__ ho1,
    __bf16* __restrict__ ho2) {           // h1 OUT planes
  __shared__ __attribute__((aligned(16))) __bf16 As[3][4096];  // 24 KiB
  __shared__ __attribute__((aligned(16))) __bf16 Bs[9][1024];  // 18 KiB

  const int tid = threadIdx.x;
  const int nwg = gridDim.x * gridDim.y;         // 512
  const int lin = blockIdx.y * gridDim.x + blockIdx.x;
  const int swz = (lin & 7) * (nwg >> 3) + (lin >> 3);
  const int bm = (swz / gridDim.x) * 128;
  const int bn = (swz % gridDim.x) * 32;
  const int lane = tid & 63;
  const int w  = tid >> 6;
  const int wm = w & 1;
  const int wn = w >> 1;
  const int l15 = lane & 15;
  const int kge = (lane >> 4) * 8;

  const int srow = tid >> 2;
  const int sge  = (tid & 3) * 8;
  const __bf16* tpX[3];
  tpX[0] = x0 + (size_t)(bm + srow) * 512 + sge;
  tpX[1] = x1 + (size_t)(bm + srow) * 512 + sge;
  tpX[2] = x2 + (size_t)(bm + srow) * 512 + sge;
  const __bf16* tpH[3];
  tpH[0] = hi0 + (size_t)(bm + srow) * 512 + sge;
  tpH[1] = hi1 + (size_t)(bm + srow) * 512 + sge;
  tpH[2] = hi2 + (size_t)(bm + srow) * 512 + sge;

  const int bcol = lane >> 2;
  const int bge  = (lane & 3) * 8;

  int aoff[4];
#pragma unroll
  for (int i = 0; i < 4; ++i)
    aoff[i] = (wm * 64 + i * 16 + l15) * 32 + kge;
  const int boff = (wn * 16 + l15) * 32 + kge;

  f32x4 acci[3][4] = {};   // gi [gate][mi]
  f32x4 acch[3][4] = {};   // gh

  for (int s = 0; s < 16; ++s) {
    const int k0 = s * 32;
    // ---- phase 1: gi (x-planes, w_ih1) ----
#pragma unroll
    for (int p = 0; p < 3; ++p) {
      gl_lds16(tpX[p] + k0,                    &As[p][w * 512]);
      gl_lds16(tpX[p] + (size_t)64 * 512 + k0, &As[p][2048 + w * 512]);
    }
    for (int qq = w; qq < 9; qq += 4) {
      const int gg = qq / 3, pp = qq - gg * 3;
      const __bf16* wp = (pp == 0) ? wi0 : (pp == 1) ? wi1 : wi2;
      const __bf16* src = wp + (size_t)(gg * 512 + bn + bcol) * 512 + bge + k0;
      gl_lds16(src,                    &Bs[qq][0]);
      gl_lds16(src + (size_t)16 * 512, &Bs[qq][512]);
    }
    __syncthreads();
    {
      bf16x8 Af[3][4];
#pragma unroll
      for (int mi = 0; mi < 4; ++mi) {
        Af[0][mi] = *(const bf16x8*)&As[0][aoff[mi]];
        Af[1][mi] = *(const bf16x8*)&As[1][aoff[mi]];
        Af[2][mi] = *(const bf16x8*)&As[2][aoff[mi]];
      }
#pragma unroll
      for (int gg = 0; gg < 3; ++gg) {
        bf16x8 B0 = *(const bf16x8*)&Bs[gg * 3 + 0][boff];
        bf16x8 B1 = *(const bf16x8*)&Bs[gg * 3 + 1][boff];
        bf16x8 B2 = *(const bf16x8*)&Bs[gg * 3 + 2][boff];
#pragma unroll
        for (int mi = 0; mi < 4; ++mi) {
          f32x4 c = acci[gg][mi];
          MFMA9(c, Af[0][mi], Af[1][mi], Af[2][mi], B0, B1, B2);
          acci[gg][mi] = c;
        }
      }
    }
    __syncthreads();
    // ---- phase 2: gh (h1-planes, w_hh1) ----
#pragma unroll
    for (int p = 0; p < 3; ++p) {
      gl_lds16(tpH[p] + k0,                    &As[p][w * 512]);
      gl_lds16(tpH[p] + (size_t)64 * 512 + k0, &As[p][2048 + w * 512]);
    }
    for (int qq = w; qq < 9; qq += 4) {
      const int gg = qq / 3, pp = qq - gg * 3;
      const __bf16* wp = (pp == 0) ? wh0 : (pp == 1) ? wh1 : wh2;
      const __bf16* src = wp + (size_t)(gg * 512 + bn + bcol) * 512 + bge + k0;
      gl_lds16(src,                    &Bs[qq][0]);
      gl_lds16(src + (size_t)16 * 512, &Bs[qq][512]);
    }
    __syncthreads();
    {
      bf16x8 Hf[3][4];
#pragma unroll
      for (int mi = 0; mi < 4; ++mi) {
        Hf[0][mi] = *(const bf16x8*)&As[0][aoff[mi]];
        Hf[1][mi] = *(const bf16x8*)&As[1][aoff[mi]];
        Hf[2][mi] = *(const bf16x8*)&As[2][aoff[mi]];
      }
#pragma unroll
      for (int gg = 0; gg < 3; ++gg) {
        bf16x8 B0 = *(const bf16x8*)&Bs[gg * 3 + 0][boff];
        bf16x8 B1 = *(const bf16x8*)&Bs[gg * 3 + 1][boff];
        bf16x8 B2 = *(const bf16x8*)&Bs[gg * 3 + 2][boff];
#pragma unroll
        for (int mi = 0; mi < 4; ++mi) {
          f32x4 c = acch[gg][mi];
          MFMA9(c, Hf[0][mi], Hf[1][mi], Hf[2][mi], B0, B1, B2);
          acch[gg][mi] = c;
        }
      }
    }
    __syncthreads();
  }

  const int col = bn + wn * 16 + l15;
  const float bir = bias_i[col];
  const float biz = bias_i[512 + col];
  const float bin = bias_i[1024 + col];
  const float bhr = bias_h[col];
  const float bhz = bias_h[512 + col];
  const float bhn = bias_h[1024 + col];
#pragma unroll
  for (int mi = 0; mi < 4; ++mi) {
    const int row0 = bm + wm * 64 + mi * 16 + (lane >> 4) * 4;
#pragma unroll
    for (int rr = 0; rr < 4; ++rr) {
      const int row = row0 + rr;
      const size_t idx = (size_t)row * 512 + col;
      float hold = __fadd_rn(__fadd_rn((float)hi0[idx], (float)hi1[idx]),
                             (float)hi2[idx]);
      float hnew = gru_h(acci[0][mi][rr] + bir, acci[1][mi][rr] + biz,
                         acci[2][mi][rr] + bin,
                         acch[0][mi][rr] + bhr, acch[1][mi][rr] + bhz,
                         acch[2][mi][rr] + bhn, hold);
      __bf16 s0, s1, s2;
      split3(hnew, s0, s1, s2);
      ho0[idx] = s0; ho1[idx] = s1; ho2[idx] = s2;
    }
  }
}

// ---------------- splitters / transpose -------------------------------------
__global__ __launch_bounds__(256) void k_split(
    const float* __restrict__ in, __bf16* __restrict__ p0,
    __bf16* __restrict__ p1, __bf16* __restrict__ p2, int total) {
  int i = blockIdx.x * 256 + threadIdx.x;
  if (i >= total) return;
  __bf16 a0, a1, a2;
  split3(in[i], a0, a1, a2);
  p0[i] = a0; p1[i] = a1; p2[i] = a2;
}

__global__ __launch_bounds__(256) void k_transpose(
    const float* __restrict__ in, float* __restrict__ out, int R, int C) {
  __shared__ float tile[32][33];
  int c0 = blockIdx.x * 32, r0 = blockIdx.y * 32;
  int x = threadIdx.x, y0 = threadIdx.y;
  for (int i = y0; i < 32; i += 8) {
    int r = r0 + i, c = c0 + x;
    tile[i][x] = (r < R && c < C) ? in[(size_t)r * C + c] : 0.0f;
  }
  __syncthreads();
  for (int i = y0; i < 32; i += 8) {
    int orow = c0 + i, oc = r0 + x;
    if (orow < C && oc < R) out[(size_t)orow * R + oc] = tile[x][i];
  }
}

// ---------------- sampling (4-pass byte-radix select; proven round 12) ------
__global__ __launch_bounds__(256) void k_sample(
    const float* __restrict__ logits, int* __restrict__ cur,
    int* __restrict__ finished, int* __restrict__ outTok,
    int t, uint32_t sk0, uint32_t sk1) {
  const int row = blockIdx.x;
  const int tid = threadIdx.x;
  __shared__ float sl[kVoc];
  __shared__ uint32_t skeys[kVoc];
  __shared__ int  cnt[256];
  __shared__ int  sfx[257];
  __shared__ int  wtot[4];
  __shared__ uint32_t sPrefix;
  __shared__ int  sNeed;
  __shared__ float redf[4];
  __shared__ int   redix[4];

  const float* lp = logits + (size_t)row * kVoc;
  for (int c = tid; c < kVoc; c += 256) {
    float v = lp[c];
    if (c == kBos || c == kPad) v = kNeg;
    if (c == kEos && t < 1 + kEffMin) v = kNeg;
    sl[c] = v;
    uint32_t u = __float_as_uint(v);
    skeys[c] = u ^ ((u >> 31) ? 0xFFFFFFFFu : 0x80000000u);
  }
  __syncthreads();

  uint32_t prefix = 0u;
  int need = kTopK;
  const int lane = tid & 63, wv = tid >> 6;
  for (int by = 3; by >= 0; --by) {
    cnt[tid] = 0;
    __syncthreads();
    const int sh = by * 8;
    const uint32_t hiMask = (by == 3) ? 0u : (0xFFFFFFFFu << (sh + 8));
    for (int c = tid; c < kVoc; c += 256) {
      uint32_t k = skeys[c];
      if ((k & hiMask) == prefix) atomicAdd(&cnt[(k >> sh) & 255], 1);
    }
    __syncthreads();
    int val = cnt[tid];
#pragma unroll
    for (int off = 1; off < 64; off <<= 1) {
      int other = __shfl_down(val, off, 64);
      if (lane + off < 64) val += other;
    }
    int wt = __shfl(val, 0, 64);
    if (lane == 0) wtot[wv] = wt;
    __syncthreads();
    int tail = 0;
    for (int u = wv + 1; u < 4; ++u) tail += wtot[u];
    sfx[tid] = val + tail;
    if (tid == 0) sfx[256] = 0;
    __syncthreads();
    if (sfx[tid] >= need && sfx[tid + 1] < need) {
      sPrefix = prefix | ((uint32_t)tid << sh);
      sNeed = need - sfx[tid + 1];
    }
    __syncthreads();
    prefix = sPrefix;
    need = sNeed;
    __syncthreads();
  }

  float best = -3.4e38f; int bidx = kVoc;
  for (int c = tid; c < kVoc; c += 256) {
    if (skeys[c] >= prefix) {
      uint32_t idx = (uint32_t)row * (uint32_t)kVoc + (uint32_t)c;
      uint32_t w1, w2, bits;
#if PARTITIONABLE
      tf2x32(sk0, sk1, 0u, idx, w1, w2);
      bits = w1 ^ w2;
#else
      const uint32_t HH = (uint32_t)((uint64_t)kBatch * kVoc / 2);
      if (idx < HH) { tf2x32(sk0, sk1, idx, idx + HH, w1, w2); bits = w1; }
      else          { tf2x32(sk0, sk1, idx - HH, idx, w1, w2); bits = w2; }
#endif
      uint32_t fb = (bits >> 9) | 0x3f800000u;
      float uf = __fsub_rn(__uint_as_float(fb), 1.0f);
      if (uf == 0.0f) uf = kTiny;
      float g = -logf(-logf(uf));
      float tot = __fadd_rn(g, sl[c]);
      if (tot > best || (tot == best && c < bidx)) { best = tot; bidx = c; }
    }
  }
#pragma unroll
  for (int off = 32; off; off >>= 1) {
    float ov = __shfl_down(best, off, 64);
    int   oi = __shfl_down(bidx, off, 64);
    if (ov > best || (ov == best && oi < bidx)) { best = ov; bidx = oi; }
  }
  if ((tid & 63) == 0) { redf[tid >> 6] = best; redix[tid >> 6] = bidx; }
  __syncthreads();
  if (tid == 0) {
    for (int w = 1; w < 4; ++w) {
      if (redf[w] > best || (redf[w] == best && redix[w] < bidx)) {
        best = redf[w]; bidx = redix[w];
      }
    }
    int fin = finished[row];
    int nxt = fin ? kPad : bidx;
    outTok[(size_t)row * kMaxLen + t] = nxt;
    cur[row] = nxt;
    finished[row] = fin | (nxt == kEos);
  }
}

__global__ __launch_bounds__(256) void k_init(int* cur, int* finished, int* outTok) {
  int i = blockIdx.x * 256 + threadIdx.x;
  if (i < kBatch) {
    cur[i] = kBos;
    finished[i] = 0;
    outTok[(size_t)i * kMaxLen] = kBos;
  }
}

extern "C" void kernel_launch(void* const* d_in, const int* in_sizes, int n_in,
                              void* d_out, int out_size, void* d_ws, size_t ws_size,
                              hipStream_t stream) {
  (void)in_sizes; (void)n_in; (void)out_size; (void)ws_size;
  const float* z      = (const float*)d_in[0];
  const float* embed  = (const float*)d_in[1];
  const float* w_lh   = (const float*)d_in[2];
  const float* b_lh   = (const float*)d_in[3];
  const float* w_ih0  = (const float*)d_in[4];
  const float* w_hh0  = (const float*)d_in[5];
  const float* b_ih0  = (const float*)d_in[6];
  const float* b_hh0  = (const float*)d_in[7];
  const float* w_ih1  = (const float*)d_in[8];
  const float* w_hh1  = (const float*)d_in[9];
  const float* b_ih1  = (const float*)d_in[10];
  const float* b_hh1  = (const float*)d_in[11];
  const float* w_out  = (const float*)d_in[12];
  const float* b_out  = (const float*)d_in[13];
  int* out = (int*)d_out;

  // ---- workspace: R11-proven layout (121.2 MB) ----
  char* base = (char*)d_ws;
  int* curTok   = (int*)base;
  int* finished = curTok + kBatch;
  __bf16* q = (__bf16*)(base + 32768);
  __bf16* whh0[3]; __bf16* wih1[3]; __bf16* whh1[3]; __bf16* wout[3];
  for (int i = 0; i < 3; ++i) { whh0[i] = q; q += (size_t)1536 * 512; }
  for (int i = 0; i < 3; ++i) { wih1[i] = q; q += (size_t)1536 * 512; }
  for (int i = 0; i < 3; ++i) { whh1[i] = q; q += (size_t)1536 * 512; }
  for (int i = 0; i < 3; ++i) { wout[i] = q; q += (size_t)2048 * 512; }
  __bf16* hs0A[3]; __bf16* hs1A[3];
  for (int i = 0; i < 3; ++i) { hs0A[i] = q; q += (size_t)kBatch * kHid; }
  for (int i = 0; i < 3; ++i) { hs1A[i] = q; q += (size_t)kBatch * kHid; }
  float* f = (float*)q;
  float* Eih0 = f; f += (size_t)kVoc * 1536;
  float* ghA  = f; f += (size_t)kBatch * 1536;
  float* gi1  = f; f += (size_t)kBatch * 1536;
  float* logits = ghA;                       // spans ghA + first 2M floats of gi1
  float* wt_ih0 = ghA;                       // init-only aliases
  float* wt_lh  = ghA + (size_t)128 * 1536;
  float* h0tmp  = gi1;
  float* h1tmp  = gi1 + (size_t)kBatch * kHid;
  __bf16* hs0B[3];
  { __bf16* hb = (__bf16*)f;
    for (int i = 0; i < 3; ++i) { hs0B[i] = hb; hb += (size_t)kBatch * kHid; } }
  __bf16* hs1B[3];
  { // gi1 tail beyond logits (12.6 MB free; R11-proven). Aliases h1tmp (dead
    // after init k_split, before first hs1B write at t=1).
    __bf16* hb = (__bf16*)(gi1 + (size_t)kBatch * kHid);
    for (int i = 0; i < 3; ++i) { hs1B[i] = hb; hb += (size_t)kBatch * kHid; } }

  dim3 blk(256);
  dim3 tblk(32, 8);

  // ---- one-time setup ----
  k_transpose<<<dim3(4, 48), tblk, 0, stream>>>(w_ih0, wt_ih0, 1536, 128);
  k_transpose<<<dim3(4, 32), tblk, 0, stream>>>(w_lh,  wt_lh,  1024, 128);
  k_split<<<dim3(1536 * 512 / 256), blk, 0, stream>>>(w_hh0, whh0[0], whh0[1], whh0[2], 1536 * 512);
  k_split<<<dim3(1536 * 512 / 256), blk, 0, stream>>>(w_ih1, wih1[0], wih1[1], wih1[2], 1536 * 512);
  k_split<<<dim3(1536 * 512 / 256), blk, 0, stream>>>(w_hh1, whh1[0], whh1[1], whh1[2], 1536 * 512);
  k_split<<<dim3(2048 * 512 / 256), blk, 0, stream>>>(w_out, wout[0], wout[1], wout[2], 2048 * 512);

  gemm2<0><<<dim3(12, 16, 1), blk, 0, stream>>>(
      embed, wt_ih0, b_ih0, Eih0, embed, wt_ih0, b_ih0, Eih0,
      kEmb, 1536, 1536, kEmb);
  gemm2<1><<<dim3(4, 32, 2), blk, 0, stream>>>(
      z, wt_lh,       b_lh,       h0tmp,
      z, wt_lh + 512, b_lh + 512, h1tmp,
      kEmb, 1024, kHid, kEmb);
  k_split<<<dim3(kBatch * kHid / 256), blk, 0, stream>>>(h0tmp, hs0A[0], hs0A[1], hs0A[2], kBatch * kHid);
  k_split<<<dim3(kBatch * kHid / 256), blk, 0, stream>>>(h1tmp, hs1A[0], hs1A[1], hs1A[2], kBatch * kHid);
  k_init<<<dim3((kBatch + 255) / 256), blk, 0, stream>>>(curTok, finished, out);

  uint32_t key0 = 0u, key1 = 1u;   // jax.random.key(1)
  for (int t = 1; t < kMaxLen; ++t) {
    uint32_t nk0, nk1, s0, s1;
#if PARTITIONABLE
    tf2x32(key0, key1, 0u, 0u, nk0, nk1);
    tf2x32(key0, key1, 0u, 1u, s0, s1);
#else
    uint32_t a0, b0w, a1, b1w;
    tf2x32(key0, key1, 0u, 2u, a0, b0w);
    tf2x32(key0, key1, 1u, 3u, a1, b1w);
    nk0 = a0; nk1 = a1; s0 = b0w; s1 = b1w;
#endif
    __bf16** h0in  = (t & 1) ? hs0A : hs0B;
    __bf16** h0out = (t & 1) ? hs0B : hs0A;
    __bf16** h1in  = (t & 1) ? hs1A : hs1B;
    __bf16** h1out = (t & 1) ? hs1B : hs1A;

    // layer 0: fused gh0-GEMM + gates (ping-pong h0)
    gemm_gru0<<<dim3(16, 32), blk, 0, stream>>>(
        h0in[0], h0in[1], h0in[2], whh0[0], whh0[1], whh0[2],
        b_hh0, Eih0, curTok, h0out[0], h0out[1], h0out[2]);

    // layer 1: fused gi1+gh1 GEMMs + gates (BM=128 phase-split, ping-pong h1)
    gemm_gru1<<<dim3(16, 32), blk, 0, stream>>>(
        h0out[0], h0out[1], h0out[2],
        wih1[0], wih1[1], wih1[2],
        whh1[0], whh1[1], whh1[2],
        b_ih1, b_hh1,
        h1in[0], h1in[1], h1in[2],
        h1out[0], h1out[1], h1out[2]);

    // logits + sample
    GemmArgs gla{h1out[0], h1out[1], h1out[2], wout[0], wout[1], wout[2], b_out, logits};
    gemm_mx3<<<dim3(16, 32, 1), blk, 0, stream>>>(gla, gla, 2048);
    k_sample<<<dim3(kBatch), blk, 0, stream>>>(logits, curTok, finished, out, t, s0, s1);

    key0 = nk0; key1 = nk1;
  }
}